// Round 9
// baseline (496.710 us; speedup 1.0000x reference)
//
#include <hip/hip_runtime.h>
#include <cstddef>
#include <cstdint>

// GCN 3-layer forward, MI355X.
// R9: XCD-sliced agg256. R8's agg256 (60us) was bound by compulsory per-XCD L2
// fill: every XCD gathered from the whole 25.6MB bf16 feature matrix (FETCH
// 187MB). Now 8 feature slices of 32 cols (3.2MB each, fits 4MB XCD L2);
// slice = blockIdx.x with gridDim.x=8 -> linear ids round-robin XCDs -> slice s
// pinned to XCD s. One node/wave, 4x16-lane segments gather 4 edges' 64B
// slices concurrently, shfl-reduce across segments. GEMM TPB 4->8 (B-frag
// load amortized over 8 row-tiles). Rest unchanged from R8.

#define GCN_BN_EPS 1e-5f
#define NB_CHUNK 64  // edge chunks (u16 hist safe: E/64 = 12.5k < 65535)
#define NPART 4      // node-range parts

typedef short v8bf __attribute__((ext_vector_type(8)));
typedef float v4f __attribute__((ext_vector_type(4)));

// ---------------------------------------------------------------- bf16 utils

__device__ __forceinline__ float4 unpack_bf4(uint2 u) {
  float4 r;
  r.x = __uint_as_float(u.x << 16);
  r.y = __uint_as_float(u.x & 0xffff0000u);
  r.z = __uint_as_float(u.y << 16);
  r.w = __uint_as_float(u.y & 0xffff0000u);
  return r;
}
__device__ __forceinline__ uint16_t f2bf(float f) {
  uint32_t u = __float_as_uint(f);
  return (uint16_t)((u + 0x7fffu + ((u >> 16) & 1u)) >> 16);  // RNE
}
__device__ __forceinline__ uint2 pack_bf4(float4 v) {
  uint2 r;
  r.x = (uint32_t)f2bf(v.x) | ((uint32_t)f2bf(v.y) << 16);
  r.y = (uint32_t)f2bf(v.z) | ((uint32_t)f2bf(v.w) << 16);
  return r;
}

// ---------------------------------------------------------------- preprocess

__global__ void detect_kernel(const int* __restrict__ ei, int* __restrict__ flag) {
  if (threadIdx.x == 0) {
    int nz = 0;
    for (int k = 1; k < 64; k += 2) nz |= ei[k];
    *flag = (nz == 0) ? 1 : 0;  // 1 => int64 layout (high dwords zero)
  }
}

// decode: col_[e]; pk[e] = (src, w-bits) packed uint2
__global__ void decode_kernel(const int* __restrict__ ei, const float* __restrict__ ew,
                              const int* __restrict__ flag,
                              int* __restrict__ col_, uint2* __restrict__ pk, int E) {
  int e = blockIdx.x * blockDim.x + threadIdx.x;
  if (e >= E) return;
  int r, c;
  if (*flag) { r = ei[2 * e]; c = ei[2 * (E + e)]; }
  else       { r = ei[e];     c = ei[E + e]; }
  col_[e] = c;
  pk[e] = make_uint2((unsigned)r, __float_as_uint(ew[e]));
}

// per (chunk, part): private LDS histogram (u16 packed) of this node part
__global__ __launch_bounds__(256) void hist_kernel(const int* __restrict__ col_,
                                                   int* __restrict__ hist,
                                                   int E, int n) {
  extern __shared__ unsigned int hsh[];
  const int chunk = blockIdx.x, part = blockIdx.y;
  const int npl = (n + NPART - 1) / NPART;
  const int lo = part * npl, hi = min(lo + npl, n);
  const int nw = (npl + 1) >> 1;
  for (int i = threadIdx.x; i < nw; i += 256) hsh[i] = 0u;
  __syncthreads();
  const int per = (E + NB_CHUNK - 1) / NB_CHUNK;
  const int e0 = chunk * per, e1 = min(e0 + per, E);
  for (int e = e0 + threadIdx.x; e < e1; e += 256) {
    int c = col_[e];
    if (c >= lo && c < hi) {
      int cl = c - lo;
      atomicAdd(&hsh[cl >> 1], 1u << ((cl & 1) * 16));
    }
  }
  __syncthreads();
  for (int i = threadIdx.x; i < hi - lo; i += 256)
    hist[(size_t)chunk * n + lo + i] = (int)((hsh[i >> 1] >> ((i & 1) * 16)) & 0xffffu);
}

// scan phase 1: cnt[i] = sum_chunk hist[chunk][i]; per-256-block sums -> bsum
__global__ __launch_bounds__(256) void scan1_kernel(const int* __restrict__ hist,
                                                    int* __restrict__ cnt,
                                                    int* __restrict__ bsum, int n) {
  __shared__ int ws[4];
  int i = blockIdx.x * 256 + threadIdx.x;
  int v = 0;
  if (i < n) {
    for (int b = 0; b < NB_CHUNK; ++b) v += hist[(size_t)b * n + i];
    cnt[i] = v;
  }
  int x = v;
#pragma unroll
  for (int s = 1; s < 64; s <<= 1) x += __shfl_xor(x, s, 64);
  if ((threadIdx.x & 63) == 0) ws[threadIdx.x >> 6] = x;
  __syncthreads();
  if (threadIdx.x == 0) bsum[blockIdx.x] = ws[0] + ws[1] + ws[2] + ws[3];
}

__global__ __launch_bounds__(1024) void scan2_kernel(int* __restrict__ bsum, int G,
                                                     int* __restrict__ off, int n, int E) {
  __shared__ int wsum[16], woff[16];
  int tid = threadIdx.x, lane = tid & 63, wv = tid >> 6;
  int v = (tid < G) ? bsum[tid] : 0;
  int x = v;
#pragma unroll
  for (int s = 1; s < 64; s <<= 1) { int t = __shfl_up(x, s, 64); if (lane >= s) x += t; }
  if (lane == 63) wsum[wv] = x;
  __syncthreads();
  if (wv == 0) {
    int wsv = (lane < 16) ? wsum[lane] : 0;
    int y = wsv;
#pragma unroll
    for (int s = 1; s < 16; s <<= 1) { int t = __shfl_up(y, s, 64); if (lane >= s) y += t; }
    if (lane < 16) woff[lane] = y - wsv;
  }
  __syncthreads();
  if (tid < G) bsum[tid] = x - v + woff[wv];
  if (tid == 0) off[n] = E;
}

__global__ __launch_bounds__(256) void scan3_kernel(const int* __restrict__ cnt,
                                                    const int* __restrict__ bsum,
                                                    int* __restrict__ off, int n) {
  __shared__ int wsum[4], woff[4];
  int tid = threadIdx.x, lane = tid & 63, wv = tid >> 6;
  int i = blockIdx.x * 256 + tid;
  int v = (i < n) ? cnt[i] : 0;
  int x = v;
#pragma unroll
  for (int s = 1; s < 64; s <<= 1) { int t = __shfl_up(x, s, 64); if (lane >= s) x += t; }
  if (lane == 63) wsum[wv] = x;
  __syncthreads();
  if (tid == 0) { int r = 0; for (int k = 0; k < 4; ++k) { woff[k] = r; r += wsum[k]; } }
  __syncthreads();
  if (i < n) off[i] = x - v + woff[wv] + bsum[blockIdx.x];
}

// base[b][i] = off[i] + sum_{b'<b} hist[b'][i]   (in-place over hist)
__global__ void base_kernel(const int* __restrict__ off, int* __restrict__ hist, int n) {
  int i = blockIdx.x * blockDim.x + threadIdx.x;
  if (i >= n) return;
  int run = off[i];
  for (int b = 0; b < NB_CHUNK; ++b) {
    size_t idx = (size_t)b * n + i;
    int h = hist[idx];
    hist[idx] = run;
    run += h;
  }
}

// fill: per (chunk, part) LDS cursors; single 8B packed store per edge
__global__ __launch_bounds__(256) void fill_kernel(
    const int* __restrict__ col_, const uint2* __restrict__ pk,
    const int* __restrict__ base, uint2* __restrict__ csr, int E, int n) {
  extern __shared__ int cur[];
  const int chunk = blockIdx.x, part = blockIdx.y;
  const int npl = (n + NPART - 1) / NPART;
  const int lo = part * npl, hi = min(lo + npl, n);
  for (int i = threadIdx.x; i < hi - lo; i += 256)
    cur[i] = base[(size_t)chunk * n + lo + i];
  __syncthreads();
  const int per = (E + NB_CHUNK - 1) / NB_CHUNK;
  const int e0 = chunk * per, e1 = min(e0 + per, E);
  for (int e = e0 + threadIdx.x; e < e1; e += 256) {
    int c = col_[e];
    if (c >= lo && c < hi) {
      int p = atomicAdd(&cur[c - lo], 1);
      csr[p] = pk[e];
    }
  }
}

// deg = 1 + segment-sum of weights; dinv = rsqrt(deg)
__global__ void degdinv_kernel(const int* __restrict__ off, const uint2* __restrict__ csr,
                               float* __restrict__ dinv, int n) {
  int i = blockIdx.x * blockDim.x + threadIdx.x;
  if (i >= n) return;
  float s = 1.0f;
  int p1 = off[i + 1];
  for (int p = off[i]; p < p1; ++p) s += __uint_as_float(csr[p].y);
  dinv[i] = rsqrtf(s);
}

// csr[p].y: w -> dinv[src] * w * dinv[c]   (in place)
__global__ void val_kernel(const int* __restrict__ off, uint2* __restrict__ csr,
                           const float* __restrict__ dinv, int n) {
  int i = blockIdx.x * blockDim.x + threadIdx.x;
  if (i >= n) return;
  float dc = dinv[i];
  int p1 = off[i + 1];
  for (int p = off[i]; p < p1; ++p) {
    uint2 t = csr[p];
    csr[p].y = __float_as_uint(dinv[t.x] * __uint_as_float(t.y) * dc);
  }
}

// ---------------------------------------------------------------- conversions

__global__ void conv_x_kernel(const float* __restrict__ x, uint16_t* __restrict__ xb,
                              int n4) {
  int i = blockIdx.x * blockDim.x + threadIdx.x;
  if (i >= n4) return;
  float4 v = *(const float4*)&x[(size_t)i * 4];
  *(uint2*)&xb[(size_t)i * 4] = pack_bf4(v);
}

// W[K][N] fp32 -> WT[N][K] bf16
__global__ void conv_wt_kernel(const float* __restrict__ W, uint16_t* __restrict__ WT,
                               int K, int Nc) {
  int i = blockIdx.x * blockDim.x + threadIdx.x;
  if (i >= K * Nc) return;
  int n = i / K, k = i - n * K;
  WT[i] = f2bf(W[(size_t)k * Nc + n]);
}

// ---------------------------------------------------------------- aggregation
// csr[p] = (src, val-bits): one uint2 gather per edge slot.

// D=256 bf16, XCD-SLICED: grid (8 slices, ngroups). slice=blockIdx.x so the
// round-robin block->XCD mapping pins slice s (N x 32 cols, 3.2MB) to XCD s's
// L2. One node per wave; 4 segments x 16 lanes gather 4 edges' 64B slices
// concurrently; 2-step shfl reduce across segments; seg 0 stores.
// EPI 0 plain, 1 (+bias,BN,ReLU)
template <int EPI>
__global__ __launch_bounds__(256) void agg256s_kernel(
    const uint16_t* __restrict__ hin, uint16_t* __restrict__ hout,
    const int* __restrict__ off, const uint2* __restrict__ csr,
    const float* __restrict__ dinv,
    const float* __restrict__ bias, const float* __restrict__ g,
    const float* __restrict__ be, int n) {
  const int lane = threadIdx.x & 63;
  const int seg = lane >> 4;        // 0..3
  const int l16 = lane & 15;
  const int sl = blockIdx.x;        // slice 0..7 (XCD id via round-robin)
  const int c = blockIdx.y * 4 + (threadIdx.x >> 6);
  if (c >= n) return;               // wave-uniform
  const int fb = sl * 32 + l16 * 2; // this lane's 2 features
  const int e0 = off[c], e1 = off[c + 1];
  float ax = 0.0f, ay = 0.0f;

  for (int base = e0; base < e1; base += 64) {
    int idx = base + lane;
    int rs = 0; float rv = 0.0f;    // zero-pad: row 0 x weight 0
    if (idx < e1) { uint2 ev = csr[idx]; rs = (int)ev.x; rv = __uint_as_float(ev.y); }
    const int m = min(64, e1 - base);
    const int nG = (m + 3) >> 2;    // groups of 4 edges; seg q takes edge 4g+q
    for (int gI = 0; gI < nG; ++gI) {
      int e_ = gI * 4 + seg;
      int s = __shfl(rs, e_);
      float v = __shfl(rv, e_);
      uint32_t hb = *(const uint32_t*)&hin[(size_t)s * 256 + fb];
      ax += v * __uint_as_float(hb << 16);
      ay += v * __uint_as_float(hb & 0xffff0000u);
    }
  }
  // reduce across 4 segments (lanes l16 of seg0 get the total)
  ax += __shfl_xor(ax, 16, 64); ay += __shfl_xor(ay, 16, 64);
  ax += __shfl_xor(ax, 32, 64); ay += __shfl_xor(ay, 32, 64);
  if (seg == 0) {
    const float di = dinv[c];
    const float s2 = di * di;
    uint32_t sb = *(const uint32_t*)&hin[(size_t)c * 256 + fb];
    ax += s2 * __uint_as_float(sb << 16);
    ay += s2 * __uint_as_float(sb & 0xffff0000u);
    if (EPI == 1) {
      const float bns = rsqrtf(1.0f + GCN_BN_EPS);
      ax = fmaxf((ax + bias[fb]) * g[fb] * bns + be[fb], 0.0f);
      ay = fmaxf((ay + bias[fb + 1]) * g[fb + 1] * bns + be[fb + 1], 0.0f);
    }
    *(uint32_t*)&hout[(size_t)c * 256 + fb] =
        (uint32_t)f2bf(ax) | ((uint32_t)f2bf(ay) << 16);
  }
}

// D=128 bf16: two nodes per wave (half-wave x 4 feats, 8B/lane).
// EPI 0: plain bf16 store. EPI 2: +bias, log_softmax -> fp32 out.
template <int EPI>
__global__ __launch_bounds__(256) void agg128_kernel(
    const uint16_t* __restrict__ hin, void* __restrict__ hout_,
    const int* __restrict__ off, const uint2* __restrict__ csr,
    const float* __restrict__ dinv,
    const float* __restrict__ bias, int n) {
  const int lane = threadIdx.x & 63;
  const int sub = lane & 31;
  const int hbase = lane & 32;
  const int c = blockIdx.x * 8 + (threadIdx.x >> 6) * 2 + (lane >> 5);
  const bool active = (c < n);
  const int f = sub * 4;

  int e0 = 0, e1 = 0;
  float4 acc = make_float4(0.f, 0.f, 0.f, 0.f);
  if (active) {
    e0 = off[c]; e1 = off[c + 1];
    float di = dinv[c];
    float s2 = di * di;
    float4 self = unpack_bf4(*(const uint2*)&hin[(size_t)c * 128 + f]);
    acc = make_float4(self.x * s2, self.y * s2, self.z * s2, self.w * s2);
  }
  int nch = (e1 - e0 + 31) >> 5;
  nch = max(nch, __shfl(nch, lane ^ 32));

  for (int ch = 0; ch < nch; ++ch) {
    int idx = e0 + ch * 32 + sub;
    int rs = 0; float rv = 0.0f;
    if (active && idx < e1) { uint2 ev = csr[idx]; rs = (int)ev.x; rv = __uint_as_float(ev.y); }
    int m = e1 - (e0 + ch * 32);
    m = m < 0 ? 0 : (m > 32 ? 32 : m);
    int mMax = max(m, __shfl(m, lane ^ 32));
    const int nG = (mMax + 3) >> 2;
    for (int gI = 0; gI < nG; ++gI) {
      int e_ = hbase + gI * 4;
      int s0 = __shfl(rs, e_);     float v0 = __shfl(rv, e_);
      int s1 = __shfl(rs, e_ + 1); float v1 = __shfl(rv, e_ + 1);
      int sB = __shfl(rs, e_ + 2); float v2 = __shfl(rv, e_ + 2);
      int s3 = __shfl(rs, e_ + 3); float v3 = __shfl(rv, e_ + 3);
      float4 h0 = unpack_bf4(*(const uint2*)&hin[(size_t)s0 * 128 + f]);
      float4 h1 = unpack_bf4(*(const uint2*)&hin[(size_t)s1 * 128 + f]);
      float4 h2 = unpack_bf4(*(const uint2*)&hin[(size_t)sB * 128 + f]);
      float4 h3 = unpack_bf4(*(const uint2*)&hin[(size_t)s3 * 128 + f]);
      acc.x += v0 * h0.x + v1 * h1.x + v2 * h2.x + v3 * h3.x;
      acc.y += v0 * h0.y + v1 * h1.y + v2 * h2.y + v3 * h3.y;
      acc.z += v0 * h0.z + v1 * h1.z + v2 * h2.z + v3 * h3.z;
      acc.w += v0 * h0.w + v1 * h1.w + v2 * h2.w + v3 * h3.w;
    }
  }

  if (EPI == 0) {
    uint16_t* hout = (uint16_t*)hout_;
    if (active) *(uint2*)&hout[(size_t)c * 128 + f] = pack_bf4(acc);
  } else {
    float* hout = (float*)hout_;
    float4 bi = active ? *(const float4*)&bias[f] : make_float4(0.f, 0.f, 0.f, 0.f);
    float tx = acc.x + bi.x, ty = acc.y + bi.y, tz = acc.z + bi.z, tw = acc.w + bi.w;
    float mx = fmaxf(fmaxf(tx, ty), fmaxf(tz, tw));
#pragma unroll
    for (int s = 1; s < 32; s <<= 1) mx = fmaxf(mx, __shfl_xor(mx, s, 64));
    float ex = expf(tx - mx) + expf(ty - mx) + expf(tz - mx) + expf(tw - mx);
#pragma unroll
    for (int s = 1; s < 32; s <<= 1) ex += __shfl_xor(ex, s, 64);
    float lse = logf(ex) + mx;
    if (active) {
      float4 res = make_float4(tx - lse, ty - lse, tz - lse, tw - lse);
      *(float4*)&hout[(size_t)c * 128 + f] = res;
    }
  }
}

// ---------------------------------------------------------------- MFMA GEMM
// B-stationary: wave holds B-frags for its col group across all K in registers,
// streams 16-row A-tiles with depth-2 prefetch; 4 waves/block share A rows.
template <int K, int NC, int EPI>
__global__ __launch_bounds__(256) void mfma_gemm_kernel(
    const uint16_t* __restrict__ A, const uint16_t* __restrict__ WT,
    uint16_t* __restrict__ Cb, int M, int tpb,
    const float* __restrict__ bias, const float* __restrict__ g,
    const float* __restrict__ be) {
  constexpr int CW = NC / 4;
  constexpr int NT = CW / 16;
  constexpr int KS = K / 32;
  const int lane = threadIdx.x & 63;
  const int wave = threadIdx.x >> 6;
  const int quad = lane >> 4;
  const int l16 = lane & 15;
  const int col0 = wave * CW;

  const int tiles = (M + 15) >> 4;
  int t0 = blockIdx.x * tpb;
  if (t0 >= tiles) return;
  int t1 = min(t0 + tpb, tiles);

  v8bf b[KS][NT];
#pragma unroll
  for (int ks = 0; ks < KS; ++ks)
#pragma unroll
    for (int nt = 0; nt < NT; ++nt)
      b[ks][nt] = *(const v8bf*)(WT + (size_t)(col0 + nt * 16 + l16) * K +
                                 ks * 32 + quad * 8);

  float sc[NT], o1[NT], o2[NT];
  if (EPI == 1) {
    const float bns = rsqrtf(1.0f + GCN_BN_EPS);
#pragma unroll
    for (int nt = 0; nt < NT; ++nt) {
      int col = col0 + nt * 16 + l16;
      sc[nt] = g[col] * bns; o1[nt] = bias[col]; o2[nt] = be[col];
    }
  }

  v8bf a[KS], an[KS];
  {
    int arow = min(t0 * 16 + l16, M - 1);
    const uint16_t* Ap = A + (size_t)arow * K + quad * 8;
#pragma unroll
    for (int ks = 0; ks < KS; ++ks) a[ks] = *(const v8bf*)(Ap + ks * 32);
  }
  for (int t = t0; t < t1; ++t) {
    if (t + 1 < t1) {
      int arow = min((t + 1) * 16 + l16, M - 1);
      const uint16_t* Ap = A + (size_t)arow * K + quad * 8;
#pragma unroll
      for (int ks = 0; ks < KS; ++ks) an[ks] = *(const v8bf*)(Ap + ks * 32);
    }
    v4f acc[NT];
#pragma unroll
    for (int nt = 0; nt < NT; ++nt) acc[nt] = (v4f){0.f, 0.f, 0.f, 0.f};
#pragma unroll
    for (int ks = 0; ks < KS; ++ks)
#pragma unroll
      for (int nt = 0; nt < NT; ++nt)
        acc[nt] = __builtin_amdgcn_mfma_f32_16x16x32_bf16(a[ks], b[ks][nt],
                                                          acc[nt], 0, 0, 0);
    const int row0 = t * 16 + quad * 4;
#pragma unroll
    for (int nt = 0; nt < NT; ++nt) {
      const int col = col0 + nt * 16 + l16;
#pragma unroll
      for (int r = 0; r < 4; ++r) {
        int row = row0 + r;
        if (row < M) {
          float v = acc[nt][r];
          if (EPI == 1) v = fmaxf((v + o1[nt]) * sc[nt] + o2[nt], 0.0f);
          Cb[(size_t)row * NC + col] = f2bf(v);
        }
      }
    }
#pragma unroll
    for (int ks = 0; ks < KS; ++ks) a[ks] = an[ks];
  }
}

// ---------------------------------------------------------------- launch

static inline char* carve(char*& p, size_t bytes) {
  char* r = p;
  p += (bytes + 255) & ~(size_t)255;
  return r;
}

extern "C" void kernel_launch(void* const* d_in, const int* in_sizes, int n_in,
                              void* d_out, int out_size, void* d_ws, size_t ws_size,
                              hipStream_t stream) {
  const int N = in_sizes[0] / 128;
  const int E = in_sizes[2];

  const float* x  = (const float*)d_in[0];
  const int*   ei = (const int*)d_in[1];
  const float* ew = (const float*)d_in[2];
  const float* W0 = (const float*)d_in[3];
  const float* b0 = (const float*)d_in[4];
  const float* W1 = (const float*)d_in[5];
  const float* b1 = (const float*)d_in[6];
  const float* Wl = (const float*)d_in[7];
  const float* bl = (const float*)d_in[8];
  const float* g0 = (const float*)d_in[9];
  const float* be0 = (const float*)d_in[10];
  const float* g1 = (const float*)d_in[11];
  const float* be1 = (const float*)d_in[12];
  float* out = (float*)d_out;

  char* p = (char*)d_ws;
  float*    dinv    = (float*)carve(p, (size_t)N * 4);
  int*      cnt     = (int*)carve(p, (size_t)N * 4);
  int*      off     = (int*)carve(p, (size_t)(N + 1) * 4);
  int*      flag    = (int*)carve(p, 256);
  int*      bsum    = (int*)carve(p, 1024 * 4);
  int*      col_    = (int*)carve(p, (size_t)E * 4);
  uint2*    pk      = (uint2*)carve(p, (size_t)E * 8);
  uint2*    csr     = (uint2*)carve(p, (size_t)E * 8);
  int*      hist    = (int*)carve(p, (size_t)NB_CHUNK * N * 4);  // becomes base
  uint16_t* xb16    = (uint16_t*)carve(p, (size_t)N * 128 * 2);
  uint16_t* bufR    = (uint16_t*)carve(p, (size_t)N * 128 * 2);
  uint16_t* bufP    = (uint16_t*)carve(p, (size_t)N * 256 * 2);
  uint16_t* bufQ    = (uint16_t*)carve(p, (size_t)N * 256 * 2);
  uint16_t* W0t     = (uint16_t*)carve(p, (size_t)128 * 256 * 2);
  uint16_t* W1t     = (uint16_t*)carve(p, (size_t)256 * 256 * 2);
  uint16_t* Wlt     = (uint16_t*)carve(p, (size_t)256 * 128 * 2);

  const int TB = 256;
  const int gN = (N + TB - 1) / TB;
  const int gE = (E + TB - 1) / TB;
  const int gW8 = (N + 7) / 8;
  const dim3 gS(8, (N + 3) / 4);     // sliced agg256: 8 slices x node groups
  const int tiles = (N + 15) / 16;
  const int TPB = 8;                 // row-tiles per block (B-frag amortization)
  const int gG = (tiles + TPB - 1) / TPB;
  const int npl = (N + NPART - 1) / NPART;
  const size_t ldsHist = (size_t)((npl + 1) / 2) * 4;  // 25KB
  const size_t ldsFill = (size_t)npl * 4;              // 50KB
  const dim3 gHF(NB_CHUNK, NPART);

  // CSC build (zero global atomics, partitioned for occupancy)
  detect_kernel<<<1, 64, 0, stream>>>(ei, flag);
  decode_kernel<<<gE, TB, 0, stream>>>(ei, ew, flag, col_, pk, E);
  hist_kernel<<<gHF, TB, ldsHist, stream>>>(col_, hist, E, N);
  scan1_kernel<<<gN, TB, 0, stream>>>(hist, cnt, bsum, N);
  scan2_kernel<<<1, 1024, 0, stream>>>(bsum, gN, off, N, E);
  scan3_kernel<<<gN, TB, 0, stream>>>(cnt, bsum, off, N);
  base_kernel<<<gN, TB, 0, stream>>>(off, hist, N);
  fill_kernel<<<gHF, TB, ldsFill, stream>>>(col_, pk, hist, csr, E, N);
  degdinv_kernel<<<gN, TB, 0, stream>>>(off, csr, dinv, N);
  val_kernel<<<gN, TB, 0, stream>>>(off, csr, dinv, N);

  // conversions
  conv_x_kernel<<<(N * 32 + TB - 1) / TB, TB, 0, stream>>>(x, xb16, N * 32);
  conv_wt_kernel<<<(128 * 256 + TB - 1) / TB, TB, 0, stream>>>(W0, W0t, 128, 256);
  conv_wt_kernel<<<(256 * 256 + TB - 1) / TB, TB, 0, stream>>>(W1, W1t, 256, 256);
  conv_wt_kernel<<<(256 * 128 + TB - 1) / TB, TB, 0, stream>>>(Wl, Wlt, 256, 128);

  // layer 0: agg(xb16,128) -> bufR; MFMA GEMM0 +BN0+ReLU -> bufP[N,256]
  agg128_kernel<0><<<gW8, 256, 0, stream>>>(xb16, bufR, off, csr, dinv, nullptr, N);
  mfma_gemm_kernel<128, 256, 1><<<gG, 256, 0, stream>>>(bufR, W0t, bufP, N, TPB,
                                                        b0, g0, be0);
  // layer 1: GEMM1 -> bufQ; sliced agg256 +b1+BN1+ReLU -> bufP
  mfma_gemm_kernel<256, 256, 0><<<gG, 256, 0, stream>>>(bufP, W1t, bufQ, N, TPB,
                                                        nullptr, nullptr, nullptr);
  agg256s_kernel<1><<<gS, 256, 0, stream>>>(bufQ, bufP, off, csr, dinv,
                                            b1, g1, be1, N);
  // layer 2: GEMM2 -> bufR; agg128 +bl+log_softmax -> out (fp32)
  mfma_gemm_kernel<256, 128, 0><<<gG, 256, 0, stream>>>(bufP, Wlt, bufR, N, TPB,
                                                        nullptr, nullptr, nullptr);
  agg128_kernel<2><<<gW8, 256, 0, stream>>>(bufR, out, off, csr, dinv, bl, N);
}

// Round 10
// 384.595 us; speedup vs baseline: 1.2915x; 1.2915x over previous
//
#include <hip/hip_runtime.h>
#include <cstddef>
#include <cstdint>

// GCN 3-layer forward, MI355X.
// R10: revert R9's XCD-sliced agg256 (regression 60->176us: 8x metadata
// re-read + 8x per-edge instruction count; blockIdx->XCD pinning didn't hold,
// FETCH rose 187->221MB). Back to R8's full-row agg256 (one node/wave, 8B/lane
// gathers, compulsory 187MB per-XCD fill at ~3.7TB/s). Keep GEMM TPB=8
// (B-frag amortization, ~20us win in R9). CSC build from R8.

#define GCN_BN_EPS 1e-5f
#define NB_CHUNK 64  // edge chunks (u16 hist safe: E/64 = 12.5k < 65535)
#define NPART 4      // node-range parts

typedef short v8bf __attribute__((ext_vector_type(8)));
typedef float v4f __attribute__((ext_vector_type(4)));

// ---------------------------------------------------------------- bf16 utils

__device__ __forceinline__ float4 unpack_bf4(uint2 u) {
  float4 r;
  r.x = __uint_as_float(u.x << 16);
  r.y = __uint_as_float(u.x & 0xffff0000u);
  r.z = __uint_as_float(u.y << 16);
  r.w = __uint_as_float(u.y & 0xffff0000u);
  return r;
}
__device__ __forceinline__ uint16_t f2bf(float f) {
  uint32_t u = __float_as_uint(f);
  return (uint16_t)((u + 0x7fffu + ((u >> 16) & 1u)) >> 16);  // RNE
}
__device__ __forceinline__ uint2 pack_bf4(float4 v) {
  uint2 r;
  r.x = (uint32_t)f2bf(v.x) | ((uint32_t)f2bf(v.y) << 16);
  r.y = (uint32_t)f2bf(v.z) | ((uint32_t)f2bf(v.w) << 16);
  return r;
}

// ---------------------------------------------------------------- preprocess

__global__ void detect_kernel(const int* __restrict__ ei, int* __restrict__ flag) {
  if (threadIdx.x == 0) {
    int nz = 0;
    for (int k = 1; k < 64; k += 2) nz |= ei[k];
    *flag = (nz == 0) ? 1 : 0;  // 1 => int64 layout (high dwords zero)
  }
}

// decode: col_[e]; pk[e] = (src, w-bits) packed uint2
__global__ void decode_kernel(const int* __restrict__ ei, const float* __restrict__ ew,
                              const int* __restrict__ flag,
                              int* __restrict__ col_, uint2* __restrict__ pk, int E) {
  int e = blockIdx.x * blockDim.x + threadIdx.x;
  if (e >= E) return;
  int r, c;
  if (*flag) { r = ei[2 * e]; c = ei[2 * (E + e)]; }
  else       { r = ei[e];     c = ei[E + e]; }
  col_[e] = c;
  pk[e] = make_uint2((unsigned)r, __float_as_uint(ew[e]));
}

// per (chunk, part): private LDS histogram (u16 packed) of this node part
__global__ __launch_bounds__(256) void hist_kernel(const int* __restrict__ col_,
                                                   int* __restrict__ hist,
                                                   int E, int n) {
  extern __shared__ unsigned int hsh[];
  const int chunk = blockIdx.x, part = blockIdx.y;
  const int npl = (n + NPART - 1) / NPART;
  const int lo = part * npl, hi = min(lo + npl, n);
  const int nw = (npl + 1) >> 1;
  for (int i = threadIdx.x; i < nw; i += 256) hsh[i] = 0u;
  __syncthreads();
  const int per = (E + NB_CHUNK - 1) / NB_CHUNK;
  const int e0 = chunk * per, e1 = min(e0 + per, E);
  for (int e = e0 + threadIdx.x; e < e1; e += 256) {
    int c = col_[e];
    if (c >= lo && c < hi) {
      int cl = c - lo;
      atomicAdd(&hsh[cl >> 1], 1u << ((cl & 1) * 16));
    }
  }
  __syncthreads();
  for (int i = threadIdx.x; i < hi - lo; i += 256)
    hist[(size_t)chunk * n + lo + i] = (int)((hsh[i >> 1] >> ((i & 1) * 16)) & 0xffffu);
}

// scan phase 1: cnt[i] = sum_chunk hist[chunk][i]; per-256-block sums -> bsum
__global__ __launch_bounds__(256) void scan1_kernel(const int* __restrict__ hist,
                                                    int* __restrict__ cnt,
                                                    int* __restrict__ bsum, int n) {
  __shared__ int ws[4];
  int i = blockIdx.x * 256 + threadIdx.x;
  int v = 0;
  if (i < n) {
    for (int b = 0; b < NB_CHUNK; ++b) v += hist[(size_t)b * n + i];
    cnt[i] = v;
  }
  int x = v;
#pragma unroll
  for (int s = 1; s < 64; s <<= 1) x += __shfl_xor(x, s, 64);
  if ((threadIdx.x & 63) == 0) ws[threadIdx.x >> 6] = x;
  __syncthreads();
  if (threadIdx.x == 0) bsum[blockIdx.x] = ws[0] + ws[1] + ws[2] + ws[3];
}

__global__ __launch_bounds__(1024) void scan2_kernel(int* __restrict__ bsum, int G,
                                                     int* __restrict__ off, int n, int E) {
  __shared__ int wsum[16], woff[16];
  int tid = threadIdx.x, lane = tid & 63, wv = tid >> 6;
  int v = (tid < G) ? bsum[tid] : 0;
  int x = v;
#pragma unroll
  for (int s = 1; s < 64; s <<= 1) { int t = __shfl_up(x, s, 64); if (lane >= s) x += t; }
  if (lane == 63) wsum[wv] = x;
  __syncthreads();
  if (wv == 0) {
    int wsv = (lane < 16) ? wsum[lane] : 0;
    int y = wsv;
#pragma unroll
    for (int s = 1; s < 16; s <<= 1) { int t = __shfl_up(y, s, 64); if (lane >= s) y += t; }
    if (lane < 16) woff[lane] = y - wsv;
  }
  __syncthreads();
  if (tid < G) bsum[tid] = x - v + woff[wv];
  if (tid == 0) off[n] = E;
}

__global__ __launch_bounds__(256) void scan3_kernel(const int* __restrict__ cnt,
                                                    const int* __restrict__ bsum,
                                                    int* __restrict__ off, int n) {
  __shared__ int wsum[4], woff[4];
  int tid = threadIdx.x, lane = tid & 63, wv = tid >> 6;
  int i = blockIdx.x * 256 + tid;
  int v = (i < n) ? cnt[i] : 0;
  int x = v;
#pragma unroll
  for (int s = 1; s < 64; s <<= 1) { int t = __shfl_up(x, s, 64); if (lane >= s) x += t; }
  if (lane == 63) wsum[wv] = x;
  __syncthreads();
  if (tid == 0) { int r = 0; for (int k = 0; k < 4; ++k) { woff[k] = r; r += wsum[k]; } }
  __syncthreads();
  if (i < n) off[i] = x - v + woff[wv] + bsum[blockIdx.x];
}

// base[b][i] = off[i] + sum_{b'<b} hist[b'][i]   (in-place over hist)
__global__ void base_kernel(const int* __restrict__ off, int* __restrict__ hist, int n) {
  int i = blockIdx.x * blockDim.x + threadIdx.x;
  if (i >= n) return;
  int run = off[i];
  for (int b = 0; b < NB_CHUNK; ++b) {
    size_t idx = (size_t)b * n + i;
    int h = hist[idx];
    hist[idx] = run;
    run += h;
  }
}

// fill: per (chunk, part) LDS cursors; single 8B packed store per edge
__global__ __launch_bounds__(256) void fill_kernel(
    const int* __restrict__ col_, const uint2* __restrict__ pk,
    const int* __restrict__ base, uint2* __restrict__ csr, int E, int n) {
  extern __shared__ int cur[];
  const int chunk = blockIdx.x, part = blockIdx.y;
  const int npl = (n + NPART - 1) / NPART;
  const int lo = part * npl, hi = min(lo + npl, n);
  for (int i = threadIdx.x; i < hi - lo; i += 256)
    cur[i] = base[(size_t)chunk * n + lo + i];
  __syncthreads();
  const int per = (E + NB_CHUNK - 1) / NB_CHUNK;
  const int e0 = chunk * per, e1 = min(e0 + per, E);
  for (int e = e0 + threadIdx.x; e < e1; e += 256) {
    int c = col_[e];
    if (c >= lo && c < hi) {
      int p = atomicAdd(&cur[c - lo], 1);
      csr[p] = pk[e];
    }
  }
}

// deg = 1 + segment-sum of weights; dinv = rsqrt(deg)
__global__ void degdinv_kernel(const int* __restrict__ off, const uint2* __restrict__ csr,
                               float* __restrict__ dinv, int n) {
  int i = blockIdx.x * blockDim.x + threadIdx.x;
  if (i >= n) return;
  float s = 1.0f;
  int p1 = off[i + 1];
  for (int p = off[i]; p < p1; ++p) s += __uint_as_float(csr[p].y);
  dinv[i] = rsqrtf(s);
}

// csr[p].y: w -> dinv[src] * w * dinv[c]   (in place)
__global__ void val_kernel(const int* __restrict__ off, uint2* __restrict__ csr,
                           const float* __restrict__ dinv, int n) {
  int i = blockIdx.x * blockDim.x + threadIdx.x;
  if (i >= n) return;
  float dc = dinv[i];
  int p1 = off[i + 1];
  for (int p = off[i]; p < p1; ++p) {
    uint2 t = csr[p];
    csr[p].y = __float_as_uint(dinv[t.x] * __uint_as_float(t.y) * dc);
  }
}

// ---------------------------------------------------------------- conversions

__global__ void conv_x_kernel(const float* __restrict__ x, uint16_t* __restrict__ xb,
                              int n4) {
  int i = blockIdx.x * blockDim.x + threadIdx.x;
  if (i >= n4) return;
  float4 v = *(const float4*)&x[(size_t)i * 4];
  *(uint2*)&xb[(size_t)i * 4] = pack_bf4(v);
}

// W[K][N] fp32 -> WT[N][K] bf16
__global__ void conv_wt_kernel(const float* __restrict__ W, uint16_t* __restrict__ WT,
                               int K, int Nc) {
  int i = blockIdx.x * blockDim.x + threadIdx.x;
  if (i >= K * Nc) return;
  int n = i / K, k = i - n * K;
  WT[i] = f2bf(W[(size_t)k * Nc + n]);
}

// ---------------------------------------------------------------- aggregation
// csr[p] = (src, val-bits): one uint2 gather per edge slot.

// D=256 bf16: one wave per node, lane holds 4 feats (8B). EPI 0 plain, 1 BN+ReLU
template <int EPI>
__global__ __launch_bounds__(256) void agg256_kernel(
    const uint16_t* __restrict__ hin, uint16_t* __restrict__ hout,
    const int* __restrict__ off, const uint2* __restrict__ csr,
    const float* __restrict__ dinv,
    const float* __restrict__ bias, const float* __restrict__ g,
    const float* __restrict__ be, int n) {
  const int lane = threadIdx.x & 63;
  const int c = blockIdx.x * 4 + (threadIdx.x >> 6);
  if (c >= n) return;
  const int f = lane * 4;
  const int e0 = off[c], e1 = off[c + 1];
  const float di = dinv[c];
  const float s2 = di * di;
  float4 self = unpack_bf4(*(const uint2*)&hin[(size_t)c * 256 + f]);
  float4 acc = make_float4(self.x * s2, self.y * s2, self.z * s2, self.w * s2);

  for (int base = e0; base < e1; base += 64) {
    int idx = base + lane;
    int rs = 0; float rv = 0.0f;                 // zero-pad: row 0 x weight 0
    if (idx < e1) { uint2 ev = csr[idx]; rs = (int)ev.x; rv = __uint_as_float(ev.y); }
    const int m = min(64, e1 - base);
    const int nG = (m + 3) >> 2;
    for (int gI = 0; gI < nG; ++gI) {
      int e_ = gI * 4;
      int s0 = __shfl(rs, e_);     float v0 = __shfl(rv, e_);
      int s1 = __shfl(rs, e_ + 1); float v1 = __shfl(rv, e_ + 1);
      int sB = __shfl(rs, e_ + 2); float v2 = __shfl(rv, e_ + 2);
      int s3 = __shfl(rs, e_ + 3); float v3 = __shfl(rv, e_ + 3);
      float4 h0 = unpack_bf4(*(const uint2*)&hin[(size_t)s0 * 256 + f]);
      float4 h1 = unpack_bf4(*(const uint2*)&hin[(size_t)s1 * 256 + f]);
      float4 h2 = unpack_bf4(*(const uint2*)&hin[(size_t)sB * 256 + f]);
      float4 h3 = unpack_bf4(*(const uint2*)&hin[(size_t)s3 * 256 + f]);
      acc.x += v0 * h0.x + v1 * h1.x + v2 * h2.x + v3 * h3.x;
      acc.y += v0 * h0.y + v1 * h1.y + v2 * h2.y + v3 * h3.y;
      acc.z += v0 * h0.z + v1 * h1.z + v2 * h2.z + v3 * h3.z;
      acc.w += v0 * h0.w + v1 * h1.w + v2 * h2.w + v3 * h3.w;
    }
  }

  if (EPI == 1) {
    const float bns = rsqrtf(1.0f + GCN_BN_EPS);
    float4 bi = *(const float4*)&bias[f];
    float4 gi = *(const float4*)&g[f];
    float4 bei = *(const float4*)&be[f];
    acc.x = fmaxf((acc.x + bi.x) * gi.x * bns + bei.x, 0.0f);
    acc.y = fmaxf((acc.y + bi.y) * gi.y * bns + bei.y, 0.0f);
    acc.z = fmaxf((acc.z + bi.z) * gi.z * bns + bei.z, 0.0f);
    acc.w = fmaxf((acc.w + bi.w) * gi.w * bns + bei.w, 0.0f);
  }
  *(uint2*)&hout[(size_t)c * 256 + f] = pack_bf4(acc);
}

// D=128 bf16: two nodes per wave (half-wave x 4 feats, 8B/lane).
// EPI 0: plain bf16 store. EPI 2: +bias, log_softmax -> fp32 out.
template <int EPI>
__global__ __launch_bounds__(256) void agg128_kernel(
    const uint16_t* __restrict__ hin, void* __restrict__ hout_,
    const int* __restrict__ off, const uint2* __restrict__ csr,
    const float* __restrict__ dinv,
    const float* __restrict__ bias, int n) {
  const int lane = threadIdx.x & 63;
  const int sub = lane & 31;
  const int hbase = lane & 32;
  const int c = blockIdx.x * 8 + (threadIdx.x >> 6) * 2 + (lane >> 5);
  const bool active = (c < n);
  const int f = sub * 4;

  int e0 = 0, e1 = 0;
  float4 acc = make_float4(0.f, 0.f, 0.f, 0.f);
  if (active) {
    e0 = off[c]; e1 = off[c + 1];
    float di = dinv[c];
    float s2 = di * di;
    float4 self = unpack_bf4(*(const uint2*)&hin[(size_t)c * 128 + f]);
    acc = make_float4(self.x * s2, self.y * s2, self.z * s2, self.w * s2);
  }
  int nch = (e1 - e0 + 31) >> 5;
  nch = max(nch, __shfl(nch, lane ^ 32));

  for (int ch = 0; ch < nch; ++ch) {
    int idx = e0 + ch * 32 + sub;
    int rs = 0; float rv = 0.0f;
    if (active && idx < e1) { uint2 ev = csr[idx]; rs = (int)ev.x; rv = __uint_as_float(ev.y); }
    int m = e1 - (e0 + ch * 32);
    m = m < 0 ? 0 : (m > 32 ? 32 : m);
    int mMax = max(m, __shfl(m, lane ^ 32));
    const int nG = (mMax + 3) >> 2;
    for (int gI = 0; gI < nG; ++gI) {
      int e_ = hbase + gI * 4;
      int s0 = __shfl(rs, e_);     float v0 = __shfl(rv, e_);
      int s1 = __shfl(rs, e_ + 1); float v1 = __shfl(rv, e_ + 1);
      int sB = __shfl(rs, e_ + 2); float v2 = __shfl(rv, e_ + 2);
      int s3 = __shfl(rs, e_ + 3); float v3 = __shfl(rv, e_ + 3);
      float4 h0 = unpack_bf4(*(const uint2*)&hin[(size_t)s0 * 128 + f]);
      float4 h1 = unpack_bf4(*(const uint2*)&hin[(size_t)s1 * 128 + f]);
      float4 h2 = unpack_bf4(*(const uint2*)&hin[(size_t)sB * 128 + f]);
      float4 h3 = unpack_bf4(*(const uint2*)&hin[(size_t)s3 * 128 + f]);
      acc.x += v0 * h0.x + v1 * h1.x + v2 * h2.x + v3 * h3.x;
      acc.y += v0 * h0.y + v1 * h1.y + v2 * h2.y + v3 * h3.y;
      acc.z += v0 * h0.z + v1 * h1.z + v2 * h2.z + v3 * h3.z;
      acc.w += v0 * h0.w + v1 * h1.w + v2 * h2.w + v3 * h3.w;
    }
  }

  if (EPI == 0) {
    uint16_t* hout = (uint16_t*)hout_;
    if (active) *(uint2*)&hout[(size_t)c * 128 + f] = pack_bf4(acc);
  } else {
    float* hout = (float*)hout_;
    float4 bi = active ? *(const float4*)&bias[f] : make_float4(0.f, 0.f, 0.f, 0.f);
    float tx = acc.x + bi.x, ty = acc.y + bi.y, tz = acc.z + bi.z, tw = acc.w + bi.w;
    float mx = fmaxf(fmaxf(tx, ty), fmaxf(tz, tw));
#pragma unroll
    for (int s = 1; s < 32; s <<= 1) mx = fmaxf(mx, __shfl_xor(mx, s, 64));
    float ex = expf(tx - mx) + expf(ty - mx) + expf(tz - mx) + expf(tw - mx);
#pragma unroll
    for (int s = 1; s < 32; s <<= 1) ex += __shfl_xor(ex, s, 64);
    float lse = logf(ex) + mx;
    if (active) {
      float4 res = make_float4(tx - lse, ty - lse, tz - lse, tw - lse);
      *(float4*)&hout[(size_t)c * 128 + f] = res;
    }
  }
}

// ---------------------------------------------------------------- MFMA GEMM
// B-stationary: wave holds B-frags for its col group across all K in registers,
// streams 16-row A-tiles with depth-2 prefetch; 4 waves/block share A rows.
template <int K, int NC, int EPI>
__global__ __launch_bounds__(256) void mfma_gemm_kernel(
    const uint16_t* __restrict__ A, const uint16_t* __restrict__ WT,
    uint16_t* __restrict__ Cb, int M, int tpb,
    const float* __restrict__ bias, const float* __restrict__ g,
    const float* __restrict__ be) {
  constexpr int CW = NC / 4;
  constexpr int NT = CW / 16;
  constexpr int KS = K / 32;
  const int lane = threadIdx.x & 63;
  const int wave = threadIdx.x >> 6;
  const int quad = lane >> 4;
  const int l16 = lane & 15;
  const int col0 = wave * CW;

  const int tiles = (M + 15) >> 4;
  int t0 = blockIdx.x * tpb;
  if (t0 >= tiles) return;
  int t1 = min(t0 + tpb, tiles);

  v8bf b[KS][NT];
#pragma unroll
  for (int ks = 0; ks < KS; ++ks)
#pragma unroll
    for (int nt = 0; nt < NT; ++nt)
      b[ks][nt] = *(const v8bf*)(WT + (size_t)(col0 + nt * 16 + l16) * K +
                                 ks * 32 + quad * 8);

  float sc[NT], o1[NT], o2[NT];
  if (EPI == 1) {
    const float bns = rsqrtf(1.0f + GCN_BN_EPS);
#pragma unroll
    for (int nt = 0; nt < NT; ++nt) {
      int col = col0 + nt * 16 + l16;
      sc[nt] = g[col] * bns; o1[nt] = bias[col]; o2[nt] = be[col];
    }
  }

  v8bf a[KS], an[KS];
  {
    int arow = min(t0 * 16 + l16, M - 1);
    const uint16_t* Ap = A + (size_t)arow * K + quad * 8;
#pragma unroll
    for (int ks = 0; ks < KS; ++ks) a[ks] = *(const v8bf*)(Ap + ks * 32);
  }
  for (int t = t0; t < t1; ++t) {
    if (t + 1 < t1) {
      int arow = min((t + 1) * 16 + l16, M - 1);
      const uint16_t* Ap = A + (size_t)arow * K + quad * 8;
#pragma unroll
      for (int ks = 0; ks < KS; ++ks) an[ks] = *(const v8bf*)(Ap + ks * 32);
    }
    v4f acc[NT];
#pragma unroll
    for (int nt = 0; nt < NT; ++nt) acc[nt] = (v4f){0.f, 0.f, 0.f, 0.f};
#pragma unroll
    for (int ks = 0; ks < KS; ++ks)
#pragma unroll
      for (int nt = 0; nt < NT; ++nt)
        acc[nt] = __builtin_amdgcn_mfma_f32_16x16x32_bf16(a[ks], b[ks][nt],
                                                          acc[nt], 0, 0, 0);
    const int row0 = t * 16 + quad * 4;
#pragma unroll
    for (int nt = 0; nt < NT; ++nt) {
      const int col = col0 + nt * 16 + l16;
#pragma unroll
      for (int r = 0; r < 4; ++r) {
        int row = row0 + r;
        if (row < M) {
          float v = acc[nt][r];
          if (EPI == 1) v = fmaxf((v + o1[nt]) * sc[nt] + o2[nt], 0.0f);
          Cb[(size_t)row * NC + col] = f2bf(v);
        }
      }
    }
#pragma unroll
    for (int ks = 0; ks < KS; ++ks) a[ks] = an[ks];
  }
}

// ---------------------------------------------------------------- launch

static inline char* carve(char*& p, size_t bytes) {
  char* r = p;
  p += (bytes + 255) & ~(size_t)255;
  return r;
}

extern "C" void kernel_launch(void* const* d_in, const int* in_sizes, int n_in,
                              void* d_out, int out_size, void* d_ws, size_t ws_size,
                              hipStream_t stream) {
  const int N = in_sizes[0] / 128;
  const int E = in_sizes[2];

  const float* x  = (const float*)d_in[0];
  const int*   ei = (const int*)d_in[1];
  const float* ew = (const float*)d_in[2];
  const float* W0 = (const float*)d_in[3];
  const float* b0 = (const float*)d_in[4];
  const float* W1 = (const float*)d_in[5];
  const float* b1 = (const float*)d_in[6];
  const float* Wl = (const float*)d_in[7];
  const float* bl = (const float*)d_in[8];
  const float* g0 = (const float*)d_in[9];
  const float* be0 = (const float*)d_in[10];
  const float* g1 = (const float*)d_in[11];
  const float* be1 = (const float*)d_in[12];
  float* out = (float*)d_out;

  char* p = (char*)d_ws;
  float*    dinv    = (float*)carve(p, (size_t)N * 4);
  int*      cnt     = (int*)carve(p, (size_t)N * 4);
  int*      off     = (int*)carve(p, (size_t)(N + 1) * 4);
  int*      flag    = (int*)carve(p, 256);
  int*      bsum    = (int*)carve(p, 1024 * 4);
  int*      col_    = (int*)carve(p, (size_t)E * 4);
  uint2*    pk      = (uint2*)carve(p, (size_t)E * 8);
  uint2*    csr     = (uint2*)carve(p, (size_t)E * 8);
  int*      hist    = (int*)carve(p, (size_t)NB_CHUNK * N * 4);  // becomes base
  uint16_t* xb16    = (uint16_t*)carve(p, (size_t)N * 128 * 2);
  uint16_t* bufR    = (uint16_t*)carve(p, (size_t)N * 128 * 2);
  uint16_t* bufP    = (uint16_t*)carve(p, (size_t)N * 256 * 2);
  uint16_t* bufQ    = (uint16_t*)carve(p, (size_t)N * 256 * 2);
  uint16_t* W0t     = (uint16_t*)carve(p, (size_t)128 * 256 * 2);
  uint16_t* W1t     = (uint16_t*)carve(p, (size_t)256 * 256 * 2);
  uint16_t* Wlt     = (uint16_t*)carve(p, (size_t)256 * 128 * 2);

  const int TB = 256;
  const int gN = (N + TB - 1) / TB;
  const int gE = (E + TB - 1) / TB;
  const int gW4 = (N + 3) / 4;   // agg256: 4 nodes/block
  const int gW8 = (N + 7) / 8;   // agg128: 8 nodes/block
  const int tiles = (N + 15) / 16;
  const int TPB = 8;             // row-tiles per block (B-frag amortization)
  const int gG = (tiles + TPB - 1) / TPB;
  const int npl = (N + NPART - 1) / NPART;
  const size_t ldsHist = (size_t)((npl + 1) / 2) * 4;  // 25KB
  const size_t ldsFill = (size_t)npl * 4;              // 50KB
  const dim3 gHF(NB_CHUNK, NPART);

  // CSC build (zero global atomics, partitioned for occupancy)
  detect_kernel<<<1, 64, 0, stream>>>(ei, flag);
  decode_kernel<<<gE, TB, 0, stream>>>(ei, ew, flag, col_, pk, E);
  hist_kernel<<<gHF, TB, ldsHist, stream>>>(col_, hist, E, N);
  scan1_kernel<<<gN, TB, 0, stream>>>(hist, cnt, bsum, N);
  scan2_kernel<<<1, 1024, 0, stream>>>(bsum, gN, off, N, E);
  scan3_kernel<<<gN, TB, 0, stream>>>(cnt, bsum, off, N);
  base_kernel<<<gN, TB, 0, stream>>>(off, hist, N);
  fill_kernel<<<gHF, TB, ldsFill, stream>>>(col_, pk, hist, csr, E, N);
  degdinv_kernel<<<gN, TB, 0, stream>>>(off, csr, dinv, N);
  val_kernel<<<gN, TB, 0, stream>>>(off, csr, dinv, N);

  // conversions
  conv_x_kernel<<<(N * 32 + TB - 1) / TB, TB, 0, stream>>>(x, xb16, N * 32);
  conv_wt_kernel<<<(128 * 256 + TB - 1) / TB, TB, 0, stream>>>(W0, W0t, 128, 256);
  conv_wt_kernel<<<(256 * 256 + TB - 1) / TB, TB, 0, stream>>>(W1, W1t, 256, 256);
  conv_wt_kernel<<<(256 * 128 + TB - 1) / TB, TB, 0, stream>>>(Wl, Wlt, 256, 128);

  // layer 0: agg(xb16,128) -> bufR; MFMA GEMM0 +BN0+ReLU -> bufP[N,256]
  agg128_kernel<0><<<gW8, 256, 0, stream>>>(xb16, bufR, off, csr, dinv, nullptr, N);
  mfma_gemm_kernel<128, 256, 1><<<gG, 256, 0, stream>>>(bufR, W0t, bufP, N, TPB,
                                                        b0, g0, be0);
  // layer 1: GEMM1 -> bufQ; agg256 +b1+BN1+ReLU -> bufP
  mfma_gemm_kernel<256, 256, 0><<<gG, 256, 0, stream>>>(bufP, W1t, bufQ, N, TPB,
                                                        nullptr, nullptr, nullptr);
  agg256_kernel<1><<<gW4, 256, 0, stream>>>(bufQ, bufP, off, csr, dinv,
                                            b1, g1, be1, N);
  // layer 2: GEMM2 -> bufR; agg128 +bl+log_softmax -> out (fp32)
  mfma_gemm_kernel<256, 128, 0><<<gG, 256, 0, stream>>>(bufP, Wlt, bufR, N, TPB,
                                                        nullptr, nullptr, nullptr);
  agg128_kernel<2><<<gW8, 256, 0, stream>>>(bufR, out, off, csr, dinv, bl, N);
}

// Round 11
// 381.908 us; speedup vs baseline: 1.3006x; 1.0070x over previous
//
#include <hip/hip_runtime.h>
#include <cstddef>
#include <cstdint>

// GCN 3-layer forward, MI355X.
// R11: single-pass CSC build + dispatch fusion (20 -> 14 kernels).
//  - decode+detect+hist fused: 64 chunk-blocks, u8-packed full-range LDS
//    histogram (50KB; per-chunk per-node count <= max degree ~50 << 255).
//  - fill single-pass: u8 relative LDS counters + scattered base[chunk][c]
//    read (200KB/block slice, L2-resident) -> one pass over pk, not 4.
//  - scan3+base fused; all dtype conversions in one kernel.
// agg256 at its structural floor (187MB compulsory per-XCD fill @ ~3.7TB/s
// random-gather ceiling = 59us); agg/GEMM (TPB=8) unchanged from R10.

#define GCN_BN_EPS 1e-5f
#define NB_CHUNK 64  // edge chunks; E/64 = 12.5k edges per chunk

typedef short v8bf __attribute__((ext_vector_type(8)));
typedef float v4f __attribute__((ext_vector_type(4)));

// ---------------------------------------------------------------- bf16 utils

__device__ __forceinline__ float4 unpack_bf4(uint2 u) {
  float4 r;
  r.x = __uint_as_float(u.x << 16);
  r.y = __uint_as_float(u.x & 0xffff0000u);
  r.z = __uint_as_float(u.y << 16);
  r.w = __uint_as_float(u.y & 0xffff0000u);
  return r;
}
__device__ __forceinline__ uint16_t f2bf(float f) {
  uint32_t u = __float_as_uint(f);
  return (uint16_t)((u + 0x7fffu + ((u >> 16) & 1u)) >> 16);  // RNE
}
__device__ __forceinline__ uint2 pack_bf4(float4 v) {
  uint2 r;
  r.x = (uint32_t)f2bf(v.x) | ((uint32_t)f2bf(v.y) << 16);
  r.y = (uint32_t)f2bf(v.z) | ((uint32_t)f2bf(v.w) << 16);
  return r;
}

// ---------------------------------------------------------------- CSC build

// fused decode + int64-detect + u8 LDS histogram (single pass per chunk)
__global__ __launch_bounds__(256) void build_hist_kernel(
    const int* __restrict__ ei, const float* __restrict__ ew,
    int* __restrict__ col_, uint2* __restrict__ pk,
    int* __restrict__ hist, int E, int n) {
  extern __shared__ unsigned int h8[];  // (n+3)/4 words, u8-packed
  __shared__ int s_flag;
  const int b = blockIdx.x;
  const int nw = (n + 3) >> 2;
  if (threadIdx.x == 0) {
    int nz = 0;
    for (int k = 1; k < 64; k += 2) nz |= ei[k];
    s_flag = (nz == 0) ? 1 : 0;  // 1 => int64 layout (high dwords zero)
  }
  for (int i = threadIdx.x; i < nw; i += 256) h8[i] = 0u;
  __syncthreads();
  const int flag = s_flag;
  const int per = (E + NB_CHUNK - 1) / NB_CHUNK;
  const int e0 = b * per, e1 = min(e0 + per, E);
  for (int e = e0 + threadIdx.x; e < e1; e += 256) {
    int r, c;
    if (flag) { r = ei[2 * e]; c = ei[2 * (E + e)]; }
    else      { r = ei[e];     c = ei[E + e]; }
    col_[e] = c;
    pk[e] = make_uint2((unsigned)r, __float_as_uint(ew[e]));
    atomicAdd(&h8[c >> 2], 1u << ((c & 3) * 8));
  }
  __syncthreads();
  for (int i = threadIdx.x; i < n; i += 256)
    hist[(size_t)b * n + i] = (int)((h8[i >> 2] >> ((i & 3) * 8)) & 0xffu);
}

// scan phase 1: cnt[i] = sum_chunk hist[chunk][i]; per-256-block sums -> bsum
__global__ __launch_bounds__(256) void scan1_kernel(const int* __restrict__ hist,
                                                    int* __restrict__ cnt,
                                                    int* __restrict__ bsum, int n) {
  __shared__ int ws[4];
  int i = blockIdx.x * 256 + threadIdx.x;
  int v = 0;
  if (i < n) {
    for (int b = 0; b < NB_CHUNK; ++b) v += hist[(size_t)b * n + i];
    cnt[i] = v;
  }
  int x = v;
#pragma unroll
  for (int s = 1; s < 64; s <<= 1) x += __shfl_xor(x, s, 64);
  if ((threadIdx.x & 63) == 0) ws[threadIdx.x >> 6] = x;
  __syncthreads();
  if (threadIdx.x == 0) bsum[blockIdx.x] = ws[0] + ws[1] + ws[2] + ws[3];
}

__global__ __launch_bounds__(1024) void scan2_kernel(int* __restrict__ bsum, int G,
                                                     int* __restrict__ off, int n, int E) {
  __shared__ int wsum[16], woff[16];
  int tid = threadIdx.x, lane = tid & 63, wv = tid >> 6;
  int v = (tid < G) ? bsum[tid] : 0;
  int x = v;
#pragma unroll
  for (int s = 1; s < 64; s <<= 1) { int t = __shfl_up(x, s, 64); if (lane >= s) x += t; }
  if (lane == 63) wsum[wv] = x;
  __syncthreads();
  if (wv == 0) {
    int wsv = (lane < 16) ? wsum[lane] : 0;
    int y = wsv;
#pragma unroll
    for (int s = 1; s < 16; s <<= 1) { int t = __shfl_up(y, s, 64); if (lane >= s) y += t; }
    if (lane < 16) woff[lane] = y - wsv;
  }
  __syncthreads();
  if (tid < G) bsum[tid] = x - v + woff[wv];
  if (tid == 0) off[n] = E;
}

// scan3 + base fused: off[i] = global exclusive prefix; then the 64-chunk
// running sum rewrites hist[b][i] -> base[b][i] (cursor start per chunk).
__global__ __launch_bounds__(256) void scan3_base_kernel(
    const int* __restrict__ cnt, const int* __restrict__ bsum,
    int* __restrict__ off, int* __restrict__ hist, int n) {
  __shared__ int wsum[4], woff[4];
  int tid = threadIdx.x, lane = tid & 63, wv = tid >> 6;
  int i = blockIdx.x * 256 + tid;
  int v = (i < n) ? cnt[i] : 0;
  int x = v;
#pragma unroll
  for (int s = 1; s < 64; s <<= 1) { int t = __shfl_up(x, s, 64); if (lane >= s) x += t; }
  if (lane == 63) wsum[wv] = x;
  __syncthreads();
  if (tid == 0) { int r = 0; for (int k = 0; k < 4; ++k) { woff[k] = r; r += wsum[k]; } }
  __syncthreads();
  if (i < n) {
    int excl = x - v + woff[wv] + bsum[blockIdx.x];
    off[i] = excl;
    int run = excl;
    for (int b = 0; b < NB_CHUNK; ++b) {
      size_t idx = (size_t)b * n + i;
      int h = hist[idx];
      hist[idx] = run;
      run += h;
    }
  }
}

// fill single-pass: u8 relative LDS counters; p = base[chunk][c] + rel
__global__ __launch_bounds__(256) void fill_kernel(
    const int* __restrict__ col_, const uint2* __restrict__ pk,
    const int* __restrict__ base, uint2* __restrict__ csr, int E, int n) {
  extern __shared__ unsigned int c8[];  // (n+3)/4 words, u8-packed counters
  const int b = blockIdx.x;
  const int nw = (n + 3) >> 2;
  for (int i = threadIdx.x; i < nw; i += 256) c8[i] = 0u;
  __syncthreads();
  const int per = (E + NB_CHUNK - 1) / NB_CHUNK;
  const int e0 = b * per, e1 = min(e0 + per, E);
  const int* bb = base + (size_t)b * n;  // 200KB slice, L2-resident
  for (int e = e0 + threadIdx.x; e < e1; e += 256) {
    int c = col_[e];
    unsigned old = atomicAdd(&c8[c >> 2], 1u << ((c & 3) * 8));
    int rel = (int)((old >> ((c & 3) * 8)) & 0xffu);
    csr[bb[c] + rel] = pk[e];
  }
}

// deg = 1 + segment-sum of weights; dinv = rsqrt(deg)
__global__ void degdinv_kernel(const int* __restrict__ off, const uint2* __restrict__ csr,
                               float* __restrict__ dinv, int n) {
  int i = blockIdx.x * blockDim.x + threadIdx.x;
  if (i >= n) return;
  float s = 1.0f;
  int p1 = off[i + 1];
  for (int p = off[i]; p < p1; ++p) s += __uint_as_float(csr[p].y);
  dinv[i] = rsqrtf(s);
}

// csr[p].y: w -> dinv[src] * w * dinv[c]   (in place)
__global__ void val_kernel(const int* __restrict__ off, uint2* __restrict__ csr,
                           const float* __restrict__ dinv, int n) {
  int i = blockIdx.x * blockDim.x + threadIdx.x;
  if (i >= n) return;
  float dc = dinv[i];
  int p1 = off[i + 1];
  for (int p = off[i]; p < p1; ++p) {
    uint2 t = csr[p];
    csr[p].y = __float_as_uint(dinv[t.x] * __uint_as_float(t.y) * dc);
  }
}

// ---------------------------------------------------------------- conversions
// One kernel: [x -> bf16 (float4 groups)] ++ [W0^T] ++ [W1^T] ++ [Wl^T]
__global__ void conv_all_kernel(const float* __restrict__ x, uint16_t* __restrict__ xb,
                                const float* __restrict__ W0, uint16_t* __restrict__ W0t,
                                const float* __restrict__ W1, uint16_t* __restrict__ W1t,
                                const float* __restrict__ Wl, uint16_t* __restrict__ Wlt,
                                int t0) {
  int i = blockIdx.x * blockDim.x + threadIdx.x;
  if (i < t0) {
    float4 v = *(const float4*)&x[(size_t)i * 4];
    *(uint2*)&xb[(size_t)i * 4] = pack_bf4(v);
    return;
  }
  int j = i - t0;
  if (j < 128 * 256) {                       // W0: K=128, Nc=256
    int nn = j >> 7, k = j & 127;
    W0t[j] = f2bf(W0[(size_t)k * 256 + nn]);
    return;
  }
  j -= 128 * 256;
  if (j < 256 * 256) {                       // W1: K=256, Nc=256
    int nn = j >> 8, k = j & 255;
    W1t[j] = f2bf(W1[(size_t)k * 256 + nn]);
    return;
  }
  j -= 256 * 256;
  if (j < 256 * 128) {                       // Wl: K=256, Nc=128
    int nn = j >> 8, k = j & 255;
    Wlt[j] = f2bf(Wl[(size_t)k * 128 + nn]);
  }
}

// ---------------------------------------------------------------- aggregation
// csr[p] = (src, val-bits): one uint2 gather per edge slot.

// D=256 bf16: one wave per node, lane holds 4 feats (8B). EPI 0 plain, 1 BN+ReLU
template <int EPI>
__global__ __launch_bounds__(256) void agg256_kernel(
    const uint16_t* __restrict__ hin, uint16_t* __restrict__ hout,
    const int* __restrict__ off, const uint2* __restrict__ csr,
    const float* __restrict__ dinv,
    const float* __restrict__ bias, const float* __restrict__ g,
    const float* __restrict__ be, int n) {
  const int lane = threadIdx.x & 63;
  const int c = blockIdx.x * 4 + (threadIdx.x >> 6);
  if (c >= n) return;
  const int f = lane * 4;
  const int e0 = off[c], e1 = off[c + 1];
  const float di = dinv[c];
  const float s2 = di * di;
  float4 self = unpack_bf4(*(const uint2*)&hin[(size_t)c * 256 + f]);
  float4 acc = make_float4(self.x * s2, self.y * s2, self.z * s2, self.w * s2);

  for (int base = e0; base < e1; base += 64) {
    int idx = base + lane;
    int rs = 0; float rv = 0.0f;                 // zero-pad: row 0 x weight 0
    if (idx < e1) { uint2 ev = csr[idx]; rs = (int)ev.x; rv = __uint_as_float(ev.y); }
    const int m = min(64, e1 - base);
    const int nG = (m + 3) >> 2;
    for (int gI = 0; gI < nG; ++gI) {
      int e_ = gI * 4;
      int s0 = __shfl(rs, e_);     float v0 = __shfl(rv, e_);
      int s1 = __shfl(rs, e_ + 1); float v1 = __shfl(rv, e_ + 1);
      int sB = __shfl(rs, e_ + 2); float v2 = __shfl(rv, e_ + 2);
      int s3 = __shfl(rs, e_ + 3); float v3 = __shfl(rv, e_ + 3);
      float4 h0 = unpack_bf4(*(const uint2*)&hin[(size_t)s0 * 256 + f]);
      float4 h1 = unpack_bf4(*(const uint2*)&hin[(size_t)s1 * 256 + f]);
      float4 h2 = unpack_bf4(*(const uint2*)&hin[(size_t)sB * 256 + f]);
      float4 h3 = unpack_bf4(*(const uint2*)&hin[(size_t)s3 * 256 + f]);
      acc.x += v0 * h0.x + v1 * h1.x + v2 * h2.x + v3 * h3.x;
      acc.y += v0 * h0.y + v1 * h1.y + v2 * h2.y + v3 * h3.y;
      acc.z += v0 * h0.z + v1 * h1.z + v2 * h2.z + v3 * h3.z;
      acc.w += v0 * h0.w + v1 * h1.w + v2 * h2.w + v3 * h3.w;
    }
  }

  if (EPI == 1) {
    const float bns = rsqrtf(1.0f + GCN_BN_EPS);
    float4 bi = *(const float4*)&bias[f];
    float4 gi = *(const float4*)&g[f];
    float4 bei = *(const float4*)&be[f];
    acc.x = fmaxf((acc.x + bi.x) * gi.x * bns + bei.x, 0.0f);
    acc.y = fmaxf((acc.y + bi.y) * gi.y * bns + bei.y, 0.0f);
    acc.z = fmaxf((acc.z + bi.z) * gi.z * bns + bei.z, 0.0f);
    acc.w = fmaxf((acc.w + bi.w) * gi.w * bns + bei.w, 0.0f);
  }
  *(uint2*)&hout[(size_t)c * 256 + f] = pack_bf4(acc);
}

// D=128 bf16: two nodes per wave (half-wave x 4 feats, 8B/lane).
// EPI 0: plain bf16 store. EPI 2: +bias, log_softmax -> fp32 out.
template <int EPI>
__global__ __launch_bounds__(256) void agg128_kernel(
    const uint16_t* __restrict__ hin, void* __restrict__ hout_,
    const int* __restrict__ off, const uint2* __restrict__ csr,
    const float* __restrict__ dinv,
    const float* __restrict__ bias, int n) {
  const int lane = threadIdx.x & 63;
  const int sub = lane & 31;
  const int hbase = lane & 32;
  const int c = blockIdx.x * 8 + (threadIdx.x >> 6) * 2 + (lane >> 5);
  const bool active = (c < n);
  const int f = sub * 4;

  int e0 = 0, e1 = 0;
  float4 acc = make_float4(0.f, 0.f, 0.f, 0.f);
  if (active) {
    e0 = off[c]; e1 = off[c + 1];
    float di = dinv[c];
    float s2 = di * di;
    float4 self = unpack_bf4(*(const uint2*)&hin[(size_t)c * 128 + f]);
    acc = make_float4(self.x * s2, self.y * s2, self.z * s2, self.w * s2);
  }
  int nch = (e1 - e0 + 31) >> 5;
  nch = max(nch, __shfl(nch, lane ^ 32));

  for (int ch = 0; ch < nch; ++ch) {
    int idx = e0 + ch * 32 + sub;
    int rs = 0; float rv = 0.0f;
    if (active && idx < e1) { uint2 ev = csr[idx]; rs = (int)ev.x; rv = __uint_as_float(ev.y); }
    int m = e1 - (e0 + ch * 32);
    m = m < 0 ? 0 : (m > 32 ? 32 : m);
    int mMax = max(m, __shfl(m, lane ^ 32));
    const int nG = (mMax + 3) >> 2;
    for (int gI = 0; gI < nG; ++gI) {
      int e_ = hbase + gI * 4;
      int s0 = __shfl(rs, e_);     float v0 = __shfl(rv, e_);
      int s1 = __shfl(rs, e_ + 1); float v1 = __shfl(rv, e_ + 1);
      int sB = __shfl(rs, e_ + 2); float v2 = __shfl(rv, e_ + 2);
      int s3 = __shfl(rs, e_ + 3); float v3 = __shfl(rv, e_ + 3);
      float4 h0 = unpack_bf4(*(const uint2*)&hin[(size_t)s0 * 128 + f]);
      float4 h1 = unpack_bf4(*(const uint2*)&hin[(size_t)s1 * 128 + f]);
      float4 h2 = unpack_bf4(*(const uint2*)&hin[(size_t)sB * 128 + f]);
      float4 h3 = unpack_bf4(*(const uint2*)&hin[(size_t)s3 * 128 + f]);
      acc.x += v0 * h0.x + v1 * h1.x + v2 * h2.x + v3 * h3.x;
      acc.y += v0 * h0.y + v1 * h1.y + v2 * h2.y + v3 * h3.y;
      acc.z += v0 * h0.z + v1 * h1.z + v2 * h2.z + v3 * h3.z;
      acc.w += v0 * h0.w + v1 * h1.w + v2 * h2.w + v3 * h3.w;
    }
  }

  if (EPI == 0) {
    uint16_t* hout = (uint16_t*)hout_;
    if (active) *(uint2*)&hout[(size_t)c * 128 + f] = pack_bf4(acc);
  } else {
    float* hout = (float*)hout_;
    float4 bi = active ? *(const float4*)&bias[f] : make_float4(0.f, 0.f, 0.f, 0.f);
    float tx = acc.x + bi.x, ty = acc.y + bi.y, tz = acc.z + bi.z, tw = acc.w + bi.w;
    float mx = fmaxf(fmaxf(tx, ty), fmaxf(tz, tw));
#pragma unroll
    for (int s = 1; s < 32; s <<= 1) mx = fmaxf(mx, __shfl_xor(mx, s, 64));
    float ex = expf(tx - mx) + expf(ty - mx) + expf(tz - mx) + expf(tw - mx);
#pragma unroll
    for (int s = 1; s < 32; s <<= 1) ex += __shfl_xor(ex, s, 64);
    float lse = logf(ex) + mx;
    if (active) {
      float4 res = make_float4(tx - lse, ty - lse, tz - lse, tw - lse);
      *(float4*)&hout[(size_t)c * 128 + f] = res;
    }
  }
}

// ---------------------------------------------------------------- MFMA GEMM
// B-stationary: wave holds B-frags for its col group across all K in registers,
// streams 16-row A-tiles with depth-2 prefetch; 4 waves/block share A rows.
template <int K, int NC, int EPI>
__global__ __launch_bounds__(256) void mfma_gemm_kernel(
    const uint16_t* __restrict__ A, const uint16_t* __restrict__ WT,
    uint16_t* __restrict__ Cb, int M, int tpb,
    const float* __restrict__ bias, const float* __restrict__ g,
    const float* __restrict__ be) {
  constexpr int CW = NC / 4;
  constexpr int NT = CW / 16;
  constexpr int KS = K / 32;
  const int lane = threadIdx.x & 63;
  const int wave = threadIdx.x >> 6;
  const int quad = lane >> 4;
  const int l16 = lane & 15;
  const int col0 = wave * CW;

  const int tiles = (M + 15) >> 4;
  int t0 = blockIdx.x * tpb;
  if (t0 >= tiles) return;
  int t1 = min(t0 + tpb, tiles);

  v8bf b[KS][NT];
#pragma unroll
  for (int ks = 0; ks < KS; ++ks)
#pragma unroll
    for (int nt = 0; nt < NT; ++nt)
      b[ks][nt] = *(const v8bf*)(WT + (size_t)(col0 + nt * 16 + l16) * K +
                                 ks * 32 + quad * 8);

  float sc[NT], o1[NT], o2[NT];
  if (EPI == 1) {
    const float bns = rsqrtf(1.0f + GCN_BN_EPS);
#pragma unroll
    for (int nt = 0; nt < NT; ++nt) {
      int col = col0 + nt * 16 + l16;
      sc[nt] = g[col] * bns; o1[nt] = bias[col]; o2[nt] = be[col];
    }
  }

  v8bf a[KS], an[KS];
  {
    int arow = min(t0 * 16 + l16, M - 1);
    const uint16_t* Ap = A + (size_t)arow * K + quad * 8;
#pragma unroll
    for (int ks = 0; ks < KS; ++ks) a[ks] = *(const v8bf*)(Ap + ks * 32);
  }
  for (int t = t0; t < t1; ++t) {
    if (t + 1 < t1) {
      int arow = min((t + 1) * 16 + l16, M - 1);
      const uint16_t* Ap = A + (size_t)arow * K + quad * 8;
#pragma unroll
      for (int ks = 0; ks < KS; ++ks) an[ks] = *(const v8bf*)(Ap + ks * 32);
    }
    v4f acc[NT];
#pragma unroll
    for (int nt = 0; nt < NT; ++nt) acc[nt] = (v4f){0.f, 0.f, 0.f, 0.f};
#pragma unroll
    for (int ks = 0; ks < KS; ++ks)
#pragma unroll
      for (int nt = 0; nt < NT; ++nt)
        acc[nt] = __builtin_amdgcn_mfma_f32_16x16x32_bf16(a[ks], b[ks][nt],
                                                          acc[nt], 0, 0, 0);
    const int row0 = t * 16 + quad * 4;
#pragma unroll
    for (int nt = 0; nt < NT; ++nt) {
      const int col = col0 + nt * 16 + l16;
#pragma unroll
      for (int r = 0; r < 4; ++r) {
        int row = row0 + r;
        if (row < M) {
          float v = acc[nt][r];
          if (EPI == 1) v = fmaxf((v + o1[nt]) * sc[nt] + o2[nt], 0.0f);
          Cb[(size_t)row * NC + col] = f2bf(v);
        }
      }
    }
#pragma unroll
    for (int ks = 0; ks < KS; ++ks) a[ks] = an[ks];
  }
}

// ---------------------------------------------------------------- launch

static inline char* carve(char*& p, size_t bytes) {
  char* r = p;
  p += (bytes + 255) & ~(size_t)255;
  return r;
}

extern "C" void kernel_launch(void* const* d_in, const int* in_sizes, int n_in,
                              void* d_out, int out_size, void* d_ws, size_t ws_size,
                              hipStream_t stream) {
  const int N = in_sizes[0] / 128;
  const int E = in_sizes[2];

  const float* x  = (const float*)d_in[0];
  const int*   ei = (const int*)d_in[1];
  const float* ew = (const float*)d_in[2];
  const float* W0 = (const float*)d_in[3];
  const float* b0 = (const float*)d_in[4];
  const float* W1 = (const float*)d_in[5];
  const float* b1 = (const float*)d_in[6];
  const float* Wl = (const float*)d_in[7];
  const float* bl = (const float*)d_in[8];
  const float* g0 = (const float*)d_in[9];
  const float* be0 = (const float*)d_in[10];
  const float* g1 = (const float*)d_in[11];
  const float* be1 = (const float*)d_in[12];
  float* out = (float*)d_out;

  char* p = (char*)d_ws;
  float*    dinv    = (float*)carve(p, (size_t)N * 4);
  int*      cnt     = (int*)carve(p, (size_t)N * 4);
  int*      off     = (int*)carve(p, (size_t)(N + 1) * 4);
  int*      bsum    = (int*)carve(p, 1024 * 4);
  int*      col_    = (int*)carve(p, (size_t)E * 4);
  uint2*    pk      = (uint2*)carve(p, (size_t)E * 8);
  uint2*    csr     = (uint2*)carve(p, (size_t)E * 8);
  int*      hist    = (int*)carve(p, (size_t)NB_CHUNK * N * 4);  // becomes base
  uint16_t* xb16    = (uint16_t*)carve(p, (size_t)N * 128 * 2);
  uint16_t* bufR    = (uint16_t*)carve(p, (size_t)N * 128 * 2);
  uint16_t* bufP    = (uint16_t*)carve(p, (size_t)N * 256 * 2);
  uint16_t* bufQ    = (uint16_t*)carve(p, (size_t)N * 256 * 2);
  uint16_t* W0t     = (uint16_t*)carve(p, (size_t)128 * 256 * 2);
  uint16_t* W1t     = (uint16_t*)carve(p, (size_t)256 * 256 * 2);
  uint16_t* Wlt     = (uint16_t*)carve(p, (size_t)256 * 128 * 2);

  const int TB = 256;
  const int gN = (N + TB - 1) / TB;
  const int gW4 = (N + 3) / 4;   // agg256: 4 nodes/block
  const int gW8 = (N + 7) / 8;   // agg128: 8 nodes/block
  const int tiles = (N + 15) / 16;
  const int TPB = 8;             // row-tiles per block (B-frag amortization)
  const int gG = (tiles + TPB - 1) / TPB;
  const size_t ldsU8 = (size_t)((N + 3) / 4) * 4;  // 50KB u8-packed bins
  const int convT0 = N * 32;                       // x float4 groups
  const int convTot = convT0 + 128 * 256 + 256 * 256 + 256 * 128;

  // CSC build: single-pass hist (fused decode+detect), scan, fused scan3+base,
  // single-pass fill (u8 relative counters + L2-resident base slice)
  build_hist_kernel<<<NB_CHUNK, TB, ldsU8, stream>>>(ei, ew, col_, pk, hist, E, N);
  scan1_kernel<<<gN, TB, 0, stream>>>(hist, cnt, bsum, N);
  scan2_kernel<<<1, 1024, 0, stream>>>(bsum, gN, off, N, E);
  scan3_base_kernel<<<gN, TB, 0, stream>>>(cnt, bsum, off, hist, N);
  fill_kernel<<<NB_CHUNK, TB, ldsU8, stream>>>(col_, pk, hist, csr, E, N);
  degdinv_kernel<<<gN, TB, 0, stream>>>(off, csr, dinv, N);
  val_kernel<<<gN, TB, 0, stream>>>(off, csr, dinv, N);

  // all conversions in one kernel
  conv_all_kernel<<<(convTot + TB - 1) / TB, TB, 0, stream>>>(
      x, xb16, W0, W0t, W1, W1t, Wl, Wlt, convT0);

  // layer 0: agg(xb16,128) -> bufR; MFMA GEMM0 +BN0+ReLU -> bufP[N,256]
  agg128_kernel<0><<<gW8, 256, 0, stream>>>(xb16, bufR, off, csr, dinv, nullptr, N);
  mfma_gemm_kernel<128, 256, 1><<<gG, 256, 0, stream>>>(bufR, W0t, bufP, N, TPB,
                                                        b0, g0, be0);
  // layer 1: GEMM1 -> bufQ; agg256 +b1+BN1+ReLU -> bufP
  mfma_gemm_kernel<256, 256, 0><<<gG, 256, 0, stream>>>(bufP, W1t, bufQ, N, TPB,
                                                        nullptr, nullptr, nullptr);
  agg256_kernel<1><<<gW4, 256, 0, stream>>>(bufQ, bufP, off, csr, dinv,
                                            b1, g1, be1, N);
  // layer 2: GEMM2 -> bufR; agg128 +bl+log_softmax -> out (fp32)
  mfma_gemm_kernel<256, 128, 0><<<gG, 256, 0, stream>>>(bufP, Wlt, bufR, N, TPB,
                                                        nullptr, nullptr, nullptr);
  agg128_kernel<2><<<gW8, 256, 0, stream>>>(bufR, out, off, csr, dinv, bl, N);
}

// Round 12
// 360.597 us; speedup vs baseline: 1.3775x; 1.0591x over previous
//
#include <hip/hip_runtime.h>
#include <cstddef>
#include <cstdint>

// GCN 3-layer forward, MI355X.
// R12: build parallelism fix. R11's build_hist/fill ran 64 blocks x 50KB LDS
// -> 25% CU coverage (R7's occupancy disease). Now 256 chunks (3125 edges
// each, counts fit u8): full CU coverage; the chunk-exclusive prefix is
// packed-u8 IN PLACE over histw (12.8MB, no 51MB base array; packed u32 adds,
// no byte carries since per-node degree < 256). fill: pos = off[c] (L2) +
// rel-prefix byte (L2) + LDS rel counter. scan2 folded into scan3_base;
// conversions folded into scan1's grid. 14 -> 12 dispatches.
// agg (bf16, compulsory-fill-bound) + B-stationary MFMA GEMMs unchanged.

#define GCN_BN_EPS 1e-5f
#define NB_CHUNK 256  // edge chunks; E/256 = 3125 edges/chunk (u8-safe counts)

typedef short v8bf __attribute__((ext_vector_type(8)));
typedef float v4f __attribute__((ext_vector_type(4)));

// ---------------------------------------------------------------- bf16 utils

__device__ __forceinline__ float4 unpack_bf4(uint2 u) {
  float4 r;
  r.x = __uint_as_float(u.x << 16);
  r.y = __uint_as_float(u.x & 0xffff0000u);
  r.z = __uint_as_float(u.y << 16);
  r.w = __uint_as_float(u.y & 0xffff0000u);
  return r;
}
__device__ __forceinline__ uint16_t f2bf(float f) {
  uint32_t u = __float_as_uint(f);
  return (uint16_t)((u + 0x7fffu + ((u >> 16) & 1u)) >> 16);  // RNE
}
__device__ __forceinline__ uint2 pack_bf4(float4 v) {
  uint2 r;
  r.x = (uint32_t)f2bf(v.x) | ((uint32_t)f2bf(v.y) << 16);
  r.y = (uint32_t)f2bf(v.z) | ((uint32_t)f2bf(v.w) << 16);
  return r;
}

// ---------------------------------------------------------------- CSC build

// fused decode + int64-detect + u8 LDS histogram; dump LDS words to histw
__global__ __launch_bounds__(256) void build_hist_kernel(
    const int* __restrict__ ei, const float* __restrict__ ew,
    int* __restrict__ col_, uint2* __restrict__ pk,
    unsigned int* __restrict__ histw, int E, int n) {
  extern __shared__ unsigned int h8[];  // nw words, u8-packed
  __shared__ int s_flag;
  const int b = blockIdx.x;
  const int nw = (n + 3) >> 2;
  if (threadIdx.x == 0) {
    int nz = 0;
    for (int k = 1; k < 64; k += 2) nz |= ei[k];
    s_flag = (nz == 0) ? 1 : 0;  // 1 => int64 layout (high dwords zero)
  }
  for (int i = threadIdx.x; i < nw; i += 256) h8[i] = 0u;
  __syncthreads();
  const int flag = s_flag;
  const int per = (E + NB_CHUNK - 1) / NB_CHUNK;
  const int e0 = b * per, e1 = min(e0 + per, E);
  for (int e = e0 + threadIdx.x; e < e1; e += 256) {
    int r, c;
    if (flag) { r = ei[2 * e]; c = ei[2 * (E + e)]; }
    else      { r = ei[e];     c = ei[E + e]; }
    col_[e] = c;
    pk[e] = make_uint2((unsigned)r, __float_as_uint(ew[e]));
    atomicAdd(&h8[c >> 2], 1u << ((c & 3) * 8));
  }
  __syncthreads();
  for (int i = threadIdx.x; i < nw; i += 256)
    histw[(size_t)b * nw + i] = h8[i];
}

// scan1 (+ conversions in surplus blocks): cntw[j] = packed byte sums over
// chunks (degree < 256, no carries); bsum[g] = per-1024-node block total.
__global__ __launch_bounds__(256) void scan1_conv_kernel(
    const unsigned int* __restrict__ histw, unsigned int* __restrict__ cntw,
    int* __restrict__ bsum, int nw, int nB,
    const float* __restrict__ x, uint16_t* __restrict__ xb,
    const float* __restrict__ W0, uint16_t* __restrict__ W0t,
    const float* __restrict__ W1, uint16_t* __restrict__ W1t,
    const float* __restrict__ Wl, uint16_t* __restrict__ Wlt,
    int t0, int convTot) {
  if (blockIdx.x >= nB) {  // conversion part
    int i = (blockIdx.x - nB) * 256 + threadIdx.x;
    if (i >= convTot) return;
    if (i < t0) {
      float4 v = *(const float4*)&x[(size_t)i * 4];
      *(uint2*)&xb[(size_t)i * 4] = pack_bf4(v);
      return;
    }
    int j = i - t0;
    if (j < 128 * 256) { int nn = j >> 7, k = j & 127; W0t[j] = f2bf(W0[(size_t)k * 256 + nn]); return; }
    j -= 128 * 256;
    if (j < 256 * 256) { int nn = j >> 8, k = j & 255; W1t[j] = f2bf(W1[(size_t)k * 256 + nn]); return; }
    j -= 256 * 256;
    if (j < 256 * 128) { int nn = j >> 8, k = j & 255; Wlt[j] = f2bf(Wl[(size_t)k * 128 + nn]); }
    return;
  }
  __shared__ int ws[4];
  const int j = blockIdx.x * 256 + threadIdx.x;
  unsigned int acc = 0;
  if (j < nw)
    for (int b = 0; b < NB_CHUNK; ++b) acc += histw[(size_t)b * nw + j];
  if (j < nw) cntw[j] = acc;
  int s = (int)((acc & 0xffu) + ((acc >> 8) & 0xffu) + ((acc >> 16) & 0xffu) + (acc >> 24));
  int x_ = s;
#pragma unroll
  for (int st = 1; st < 64; st <<= 1) x_ += __shfl_xor(x_, st, 64);
  if ((threadIdx.x & 63) == 0) ws[threadIdx.x >> 6] = x_;
  __syncthreads();
  if (threadIdx.x == 0) bsum[blockIdx.x] = ws[0] + ws[1] + ws[2] + ws[3];
}

// scan3+base: off (uint4/word) from block+global scan (bsum scanned inline,
// nB <= 64); then in-place chunk-exclusive packed-u8 prefix over histw.
__global__ __launch_bounds__(256) void scan3_base_kernel(
    const unsigned int* __restrict__ cntw, const int* __restrict__ bsum,
    int* __restrict__ off, unsigned int* __restrict__ histw,
    int nw, int nB, int n, int E) {
  __shared__ int wsum[4], woff[4];
  __shared__ int s_gbase;
  const int tid = threadIdx.x, lane = tid & 63, wv = tid >> 6;
  const int j = blockIdx.x * 256 + tid;
  unsigned int cw = (j < nw) ? cntw[j] : 0u;
  const int c0 = (int)(cw & 0xffu), c1 = (int)((cw >> 8) & 0xffu);
  const int c2 = (int)((cw >> 16) & 0xffu), c3 = (int)(cw >> 24);
  int s = c0 + c1 + c2 + c3;
  int x = s;
#pragma unroll
  for (int st = 1; st < 64; st <<= 1) { int t = __shfl_up(x, st, 64); if (lane >= st) x += t; }
  if (lane == 63) wsum[wv] = x;
  __syncthreads();
  if (tid == 0) { int r = 0; for (int k = 0; k < 4; ++k) { woff[k] = r; r += wsum[k]; } }
  if (wv == 0) {  // inline exclusive scan of bsum[0..nB) (nB <= 64)
    int v2 = (lane < nB) ? bsum[lane] : 0;
    int y = v2;
#pragma unroll
    for (int st = 1; st < 64; st <<= 1) { int t = __shfl_up(y, st, 64); if (lane >= st) y += t; }
    if (lane == blockIdx.x) s_gbase = y - v2;
  }
  __syncthreads();
  if (j < nw) {
    int excl = x - s + woff[wv] + s_gbase;
    uint4 o4;
    o4.x = excl; o4.y = excl + c0; o4.z = excl + c0 + c1; o4.w = excl + c0 + c1 + c2;
    *(uint4*)&off[4 * j] = o4;  // n % 4 == 0 assumed (n = 50000)
    unsigned int run = 0;  // packed relative prefix, bytes <= degree < 256
    for (int b = 0; b < NB_CHUNK; ++b) {
      size_t idx = (size_t)b * nw + j;
      unsigned int w = histw[idx];
      histw[idx] = run;
      run += w;
    }
  }
  if (blockIdx.x == 0 && tid == 0) off[n] = E;
}

// fill: pos = off[c] + rel-prefix byte (histw, in-place) + LDS rel counter
__global__ __launch_bounds__(256) void fill_kernel(
    const int* __restrict__ col_, const uint2* __restrict__ pk,
    const int* __restrict__ off, const unsigned int* __restrict__ histw,
    uint2* __restrict__ csr, int E, int n) {
  extern __shared__ unsigned int c8[];  // nw words, u8-packed counters
  const int b = blockIdx.x;
  const int nw = (n + 3) >> 2;
  for (int i = threadIdx.x; i < nw; i += 256) c8[i] = 0u;
  __syncthreads();
  const int per = (E + NB_CHUNK - 1) / NB_CHUNK;
  const int e0 = b * per, e1 = min(e0 + per, E);
  const unsigned int* brel = histw + (size_t)b * nw;  // 50KB slice, L2-resident
  for (int e = e0 + threadIdx.x; e < e1; e += 256) {
    int c = col_[e];
    const int sh = (c & 3) * 8;
    unsigned old = atomicAdd(&c8[c >> 2], 1u << sh);
    int rel = (int)((old >> sh) & 0xffu) + (int)((brel[c >> 2] >> sh) & 0xffu);
    csr[off[c] + rel] = pk[e];
  }
}

// deg = 1 + segment-sum of weights; dinv = rsqrt(deg)
__global__ void degdinv_kernel(const int* __restrict__ off, const uint2* __restrict__ csr,
                               float* __restrict__ dinv, int n) {
  int i = blockIdx.x * blockDim.x + threadIdx.x;
  if (i >= n) return;
  float s = 1.0f;
  int p1 = off[i + 1];
  for (int p = off[i]; p < p1; ++p) s += __uint_as_float(csr[p].y);
  dinv[i] = rsqrtf(s);
}

// csr[p].y: w -> dinv[src] * w * dinv[c]   (in place)
__global__ void val_kernel(const int* __restrict__ off, uint2* __restrict__ csr,
                           const float* __restrict__ dinv, int n) {
  int i = blockIdx.x * blockDim.x + threadIdx.x;
  if (i >= n) return;
  float dc = dinv[i];
  int p1 = off[i + 1];
  for (int p = off[i]; p < p1; ++p) {
    uint2 t = csr[p];
    csr[p].y = __float_as_uint(dinv[t.x] * __uint_as_float(t.y) * dc);
  }
}

// ---------------------------------------------------------------- aggregation
// csr[p] = (src, val-bits): one uint2 gather per edge slot.

// D=256 bf16: one wave per node, lane holds 4 feats (8B). EPI 0 plain, 1 BN+ReLU
template <int EPI>
__global__ __launch_bounds__(256) void agg256_kernel(
    const uint16_t* __restrict__ hin, uint16_t* __restrict__ hout,
    const int* __restrict__ off, const uint2* __restrict__ csr,
    const float* __restrict__ dinv,
    const float* __restrict__ bias, const float* __restrict__ g,
    const float* __restrict__ be, int n) {
  const int lane = threadIdx.x & 63;
  const int c = blockIdx.x * 4 + (threadIdx.x >> 6);
  if (c >= n) return;
  const int f = lane * 4;
  const int e0 = off[c], e1 = off[c + 1];
  const float di = dinv[c];
  const float s2 = di * di;
  float4 self = unpack_bf4(*(const uint2*)&hin[(size_t)c * 256 + f]);
  float4 acc = make_float4(self.x * s2, self.y * s2, self.z * s2, self.w * s2);

  for (int base = e0; base < e1; base += 64) {
    int idx = base + lane;
    int rs = 0; float rv = 0.0f;                 // zero-pad: row 0 x weight 0
    if (idx < e1) { uint2 ev = csr[idx]; rs = (int)ev.x; rv = __uint_as_float(ev.y); }
    const int m = min(64, e1 - base);
    const int nG = (m + 3) >> 2;
    for (int gI = 0; gI < nG; ++gI) {
      int e_ = gI * 4;
      int s0 = __shfl(rs, e_);     float v0 = __shfl(rv, e_);
      int s1 = __shfl(rs, e_ + 1); float v1 = __shfl(rv, e_ + 1);
      int sB = __shfl(rs, e_ + 2); float v2 = __shfl(rv, e_ + 2);
      int s3 = __shfl(rs, e_ + 3); float v3 = __shfl(rv, e_ + 3);
      float4 h0 = unpack_bf4(*(const uint2*)&hin[(size_t)s0 * 256 + f]);
      float4 h1 = unpack_bf4(*(const uint2*)&hin[(size_t)s1 * 256 + f]);
      float4 h2 = unpack_bf4(*(const uint2*)&hin[(size_t)sB * 256 + f]);
      float4 h3 = unpack_bf4(*(const uint2*)&hin[(size_t)s3 * 256 + f]);
      acc.x += v0 * h0.x + v1 * h1.x + v2 * h2.x + v3 * h3.x;
      acc.y += v0 * h0.y + v1 * h1.y + v2 * h2.y + v3 * h3.y;
      acc.z += v0 * h0.z + v1 * h1.z + v2 * h2.z + v3 * h3.z;
      acc.w += v0 * h0.w + v1 * h1.w + v2 * h2.w + v3 * h3.w;
    }
  }

  if (EPI == 1) {
    const float bns = rsqrtf(1.0f + GCN_BN_EPS);
    float4 bi = *(const float4*)&bias[f];
    float4 gi = *(const float4*)&g[f];
    float4 bei = *(const float4*)&be[f];
    acc.x = fmaxf((acc.x + bi.x) * gi.x * bns + bei.x, 0.0f);
    acc.y = fmaxf((acc.y + bi.y) * gi.y * bns + bei.y, 0.0f);
    acc.z = fmaxf((acc.z + bi.z) * gi.z * bns + bei.z, 0.0f);
    acc.w = fmaxf((acc.w + bi.w) * gi.w * bns + bei.w, 0.0f);
  }
  *(uint2*)&hout[(size_t)c * 256 + f] = pack_bf4(acc);
}

// D=128 bf16: two nodes per wave (half-wave x 4 feats, 8B/lane).
// EPI 0: plain bf16 store. EPI 2: +bias, log_softmax -> fp32 out.
template <int EPI>
__global__ __launch_bounds__(256) void agg128_kernel(
    const uint16_t* __restrict__ hin, void* __restrict__ hout_,
    const int* __restrict__ off, const uint2* __restrict__ csr,
    const float* __restrict__ dinv,
    const float* __restrict__ bias, int n) {
  const int lane = threadIdx.x & 63;
  const int sub = lane & 31;
  const int hbase = lane & 32;
  const int c = blockIdx.x * 8 + (threadIdx.x >> 6) * 2 + (lane >> 5);
  const bool active = (c < n);
  const int f = sub * 4;

  int e0 = 0, e1 = 0;
  float4 acc = make_float4(0.f, 0.f, 0.f, 0.f);
  if (active) {
    e0 = off[c]; e1 = off[c + 1];
    float di = dinv[c];
    float s2 = di * di;
    float4 self = unpack_bf4(*(const uint2*)&hin[(size_t)c * 128 + f]);
    acc = make_float4(self.x * s2, self.y * s2, self.z * s2, self.w * s2);
  }
  int nch = (e1 - e0 + 31) >> 5;
  nch = max(nch, __shfl(nch, lane ^ 32));

  for (int ch = 0; ch < nch; ++ch) {
    int idx = e0 + ch * 32 + sub;
    int rs = 0; float rv = 0.0f;
    if (active && idx < e1) { uint2 ev = csr[idx]; rs = (int)ev.x; rv = __uint_as_float(ev.y); }
    int m = e1 - (e0 + ch * 32);
    m = m < 0 ? 0 : (m > 32 ? 32 : m);
    int mMax = max(m, __shfl(m, lane ^ 32));
    const int nG = (mMax + 3) >> 2;
    for (int gI = 0; gI < nG; ++gI) {
      int e_ = hbase + gI * 4;
      int s0 = __shfl(rs, e_);     float v0 = __shfl(rv, e_);
      int s1 = __shfl(rs, e_ + 1); float v1 = __shfl(rv, e_ + 1);
      int sB = __shfl(rs, e_ + 2); float v2 = __shfl(rv, e_ + 2);
      int s3 = __shfl(rs, e_ + 3); float v3 = __shfl(rv, e_ + 3);
      float4 h0 = unpack_bf4(*(const uint2*)&hin[(size_t)s0 * 128 + f]);
      float4 h1 = unpack_bf4(*(const uint2*)&hin[(size_t)s1 * 128 + f]);
      float4 h2 = unpack_bf4(*(const uint2*)&hin[(size_t)sB * 128 + f]);
      float4 h3 = unpack_bf4(*(const uint2*)&hin[(size_t)s3 * 128 + f]);
      acc.x += v0 * h0.x + v1 * h1.x + v2 * h2.x + v3 * h3.x;
      acc.y += v0 * h0.y + v1 * h1.y + v2 * h2.y + v3 * h3.y;
      acc.z += v0 * h0.z + v1 * h1.z + v2 * h2.z + v3 * h3.z;
      acc.w += v0 * h0.w + v1 * h1.w + v2 * h2.w + v3 * h3.w;
    }
  }

  if (EPI == 0) {
    uint16_t* hout = (uint16_t*)hout_;
    if (active) *(uint2*)&hout[(size_t)c * 128 + f] = pack_bf4(acc);
  } else {
    float* hout = (float*)hout_;
    float4 bi = active ? *(const float4*)&bias[f] : make_float4(0.f, 0.f, 0.f, 0.f);
    float tx = acc.x + bi.x, ty = acc.y + bi.y, tz = acc.z + bi.z, tw = acc.w + bi.w;
    float mx = fmaxf(fmaxf(tx, ty), fmaxf(tz, tw));
#pragma unroll
    for (int s = 1; s < 32; s <<= 1) mx = fmaxf(mx, __shfl_xor(mx, s, 64));
    float ex = expf(tx - mx) + expf(ty - mx) + expf(tz - mx) + expf(tw - mx);
#pragma unroll
    for (int s = 1; s < 32; s <<= 1) ex += __shfl_xor(ex, s, 64);
    float lse = logf(ex) + mx;
    if (active) {
      float4 res = make_float4(tx - lse, ty - lse, tz - lse, tw - lse);
      *(float4*)&hout[(size_t)c * 128 + f] = res;
    }
  }
}

// ---------------------------------------------------------------- MFMA GEMM
// B-stationary: wave holds B-frags for its col group across all K in registers,
// streams 16-row A-tiles with depth-2 prefetch; 4 waves/block share A rows.
template <int K, int NC, int EPI>
__global__ __launch_bounds__(256) void mfma_gemm_kernel(
    const uint16_t* __restrict__ A, const uint16_t* __restrict__ WT,
    uint16_t* __restrict__ Cb, int M, int tpb,
    const float* __restrict__ bias, const float* __restrict__ g,
    const float* __restrict__ be) {
  constexpr int CW = NC / 4;
  constexpr int NT = CW / 16;
  constexpr int KS = K / 32;
  const int lane = threadIdx.x & 63;
  const int wave = threadIdx.x >> 6;
  const int quad = lane >> 4;
  const int l16 = lane & 15;
  const int col0 = wave * CW;

  const int tiles = (M + 15) >> 4;
  int t0 = blockIdx.x * tpb;
  if (t0 >= tiles) return;
  int t1 = min(t0 + tpb, tiles);

  v8bf b[KS][NT];
#pragma unroll
  for (int ks = 0; ks < KS; ++ks)
#pragma unroll
    for (int nt = 0; nt < NT; ++nt)
      b[ks][nt] = *(const v8bf*)(WT + (size_t)(col0 + nt * 16 + l16) * K +
                                 ks * 32 + quad * 8);

  float sc[NT], o1[NT], o2[NT];
  if (EPI == 1) {
    const float bns = rsqrtf(1.0f + GCN_BN_EPS);
#pragma unroll
    for (int nt = 0; nt < NT; ++nt) {
      int col = col0 + nt * 16 + l16;
      sc[nt] = g[col] * bns; o1[nt] = bias[col]; o2[nt] = be[col];
    }
  }

  v8bf a[KS], an[KS];
  {
    int arow = min(t0 * 16 + l16, M - 1);
    const uint16_t* Ap = A + (size_t)arow * K + quad * 8;
#pragma unroll
    for (int ks = 0; ks < KS; ++ks) a[ks] = *(const v8bf*)(Ap + ks * 32);
  }
  for (int t = t0; t < t1; ++t) {
    if (t + 1 < t1) {
      int arow = min((t + 1) * 16 + l16, M - 1);
      const uint16_t* Ap = A + (size_t)arow * K + quad * 8;
#pragma unroll
      for (int ks = 0; ks < KS; ++ks) an[ks] = *(const v8bf*)(Ap + ks * 32);
    }
    v4f acc[NT];
#pragma unroll
    for (int nt = 0; nt < NT; ++nt) acc[nt] = (v4f){0.f, 0.f, 0.f, 0.f};
#pragma unroll
    for (int ks = 0; ks < KS; ++ks)
#pragma unroll
      for (int nt = 0; nt < NT; ++nt)
        acc[nt] = __builtin_amdgcn_mfma_f32_16x16x32_bf16(a[ks], b[ks][nt],
                                                          acc[nt], 0, 0, 0);
    const int row0 = t * 16 + quad * 4;
#pragma unroll
    for (int nt = 0; nt < NT; ++nt) {
      const int col = col0 + nt * 16 + l16;
#pragma unroll
      for (int r = 0; r < 4; ++r) {
        int row = row0 + r;
        if (row < M) {
          float v = acc[nt][r];
          if (EPI == 1) v = fmaxf((v + o1[nt]) * sc[nt] + o2[nt], 0.0f);
          Cb[(size_t)row * NC + col] = f2bf(v);
        }
      }
    }
#pragma unroll
    for (int ks = 0; ks < KS; ++ks) a[ks] = an[ks];
  }
}

// ---------------------------------------------------------------- launch

static inline char* carve(char*& p, size_t bytes) {
  char* r = p;
  p += (bytes + 255) & ~(size_t)255;
  return r;
}

extern "C" void kernel_launch(void* const* d_in, const int* in_sizes, int n_in,
                              void* d_out, int out_size, void* d_ws, size_t ws_size,
                              hipStream_t stream) {
  const int N = in_sizes[0] / 128;
  const int E = in_sizes[2];

  const float* x  = (const float*)d_in[0];
  const int*   ei = (const int*)d_in[1];
  const float* ew = (const float*)d_in[2];
  const float* W0 = (const float*)d_in[3];
  const float* b0 = (const float*)d_in[4];
  const float* W1 = (const float*)d_in[5];
  const float* b1 = (const float*)d_in[6];
  const float* Wl = (const float*)d_in[7];
  const float* bl = (const float*)d_in[8];
  const float* g0 = (const float*)d_in[9];
  const float* be0 = (const float*)d_in[10];
  const float* g1 = (const float*)d_in[11];
  const float* be1 = (const float*)d_in[12];
  float* out = (float*)d_out;

  const int nw = (N + 3) / 4;  // histogram words (N % 4 == 0 for N=50000)

  char* p = (char*)d_ws;
  float*        dinv  = (float*)carve(p, (size_t)N * 4);
  unsigned int* cntw  = (unsigned int*)carve(p, (size_t)nw * 4);
  int*          off   = (int*)carve(p, (size_t)(N + 1) * 4);
  int*          bsum  = (int*)carve(p, 1024 * 4);
  int*          col_  = (int*)carve(p, (size_t)E * 4);
  uint2*        pk    = (uint2*)carve(p, (size_t)E * 8);
  uint2*        csr   = (uint2*)carve(p, (size_t)E * 8);
  unsigned int* histw = (unsigned int*)carve(p, (size_t)NB_CHUNK * nw * 4);
  uint16_t*     xb16  = (uint16_t*)carve(p, (size_t)N * 128 * 2);
  uint16_t*     bufR  = (uint16_t*)carve(p, (size_t)N * 128 * 2);
  uint16_t*     bufP  = (uint16_t*)carve(p, (size_t)N * 256 * 2);
  uint16_t*     bufQ  = (uint16_t*)carve(p, (size_t)N * 256 * 2);
  uint16_t*     W0t   = (uint16_t*)carve(p, (size_t)128 * 256 * 2);
  uint16_t*     W1t   = (uint16_t*)carve(p, (size_t)256 * 256 * 2);
  uint16_t*     Wlt   = (uint16_t*)carve(p, (size_t)256 * 128 * 2);

  const int TB = 256;
  const int gN = (N + TB - 1) / TB;
  const int gW4 = (N + 3) / 4;   // agg256: 4 nodes/block
  const int gW8 = (N + 7) / 8;   // agg128: 8 nodes/block
  const int tiles = (N + 15) / 16;
  const int TPB = 8;             // row-tiles per block (B-frag amortization)
  const int gG = (tiles + TPB - 1) / TPB;
  const size_t ldsU8 = (size_t)nw * 4;  // 50KB u8-packed bins
  const int nB = (nw + 255) / 256;      // scan blocks (49 <= 64, required)
  const int convT0 = N * 32;            // x float4 groups
  const int convTot = convT0 + 128 * 256 + 256 * 256 + 256 * 128;
  const int convB = (convTot + TB - 1) / TB;

  // CSC build: 256-chunk u8 build (full CU coverage), scan+conv, fused
  // scan3+base (in-place rel prefix), single-pass fill
  build_hist_kernel<<<NB_CHUNK, TB, ldsU8, stream>>>(ei, ew, col_, pk, histw, E, N);
  scan1_conv_kernel<<<nB + convB, TB, 0, stream>>>(histw, cntw, bsum, nw, nB,
                                                   x, xb16, W0, W0t, W1, W1t,
                                                   Wl, Wlt, convT0, convTot);
  scan3_base_kernel<<<nB, TB, 0, stream>>>(cntw, bsum, off, histw, nw, nB, N, E);
  fill_kernel<<<NB_CHUNK, TB, ldsU8, stream>>>(col_, pk, off, histw, csr, E, N);
  degdinv_kernel<<<gN, TB, 0, stream>>>(off, csr, dinv, N);
  val_kernel<<<gN, TB, 0, stream>>>(off, csr, dinv, N);

  // layer 0: agg(xb16,128) -> bufR; MFMA GEMM0 +BN0+ReLU -> bufP[N,256]
  agg128_kernel<0><<<gW8, 256, 0, stream>>>(xb16, bufR, off, csr, dinv, nullptr, N);
  mfma_gemm_kernel<128, 256, 1><<<gG, 256, 0, stream>>>(bufR, W0t, bufP, N, TPB,
                                                        b0, g0, be0);
  // layer 1: GEMM1 -> bufQ; agg256 +b1+BN1+ReLU -> bufP
  mfma_gemm_kernel<256, 256, 0><<<gG, 256, 0, stream>>>(bufP, W1t, bufQ, N, TPB,
                                                        nullptr, nullptr, nullptr);
  agg256_kernel<1><<<gW4, 256, 0, stream>>>(bufQ, bufP, off, csr, dinv,
                                            b1, g1, be1, N);
  // layer 2: GEMM2 -> bufR; agg128 +bl+log_softmax -> out (fp32)
  mfma_gemm_kernel<256, 128, 0><<<gG, 256, 0, stream>>>(bufP, Wlt, bufR, N, TPB,
                                                        nullptr, nullptr, nullptr);
  agg128_kernel<2><<<gW8, 256, 0, stream>>>(bufR, out, off, csr, dinv, bl, N);
}